// Round 2
// baseline (3396.758 us; speedup 1.0000x reference)
//
#include <hip/hip_runtime.h>
#include <hip/hip_bf16.h>
#include <math.h>

// EncoderRNN on MI355X. Inputs fp32, output fp32.
// R13 restructure:
//  - x-side gates batched per superstep (8 t): k_xgates (256 blocks) computes
//    Gx[t] = vh@W1ih_h + vl@W1ih_h + vh@W1ih_l reading W1ih fp32 directly
//    (cvt in-kernel) -> w1ih splits dropped from ws (-16 MB).
//  - k_embed K-split x4 (256 blocks, full machine); fp32 partials (16 MB)
//    alias the Gx ring (dead during refill); k_efin sums + bias + relu + split.
//  - k_step h-side only: 4 B-major units x 32 ct = 128 blocks; h1n stored
//    unmasked hi/lo + s mask applied in GEMM A-staging (exact for s in {0,1}).
//    P0=h1n(1-s)@w1hh_h(2A), P1=h1nh(1-s)@w1hh_l, P2=h1n*s@w2ih_h(2A),
//    P3=h2@w2hh_h(2A).
//  - k_zx folded into k_elem (inline fp64 dot).
//  ws total ~65.1 MB (fits the known 67.7-71.9 MB workspace).

typedef __attribute__((ext_vector_type(8))) short short8;
typedef __attribute__((ext_vector_type(4))) short short4v;
typedef __attribute__((ext_vector_type(4))) float f32x4;
typedef __hip_bfloat16 bf16;

__device__ __forceinline__ float sigm(float x) { return 1.0f / (1.0f + expf(-x)); }
__device__ __forceinline__ short bfbits(float x) {
  bf16 h = __float2bfloat16(x);
  return __builtin_bit_cast(short, h);
}
// fp32 x8 -> bf16 hi + residual lo in one pass
__device__ __forceinline__ void cvt8hl(const float* __restrict__ p,
                                       short8& hi, short8& lo)
{
  f32x4 a = *(const f32x4*)p;
  f32x4 b = *(const f32x4*)(p + 4);
#pragma unroll
  for (int j = 0; j < 8; ++j) {
    float x = (j < 4) ? a[j] : b[j - 4];
    bf16 h = __float2bfloat16(x);
    hi[j] = __builtin_bit_cast(short, h);
    lo[j] = bfbits(x - __bfloat162float(h));
  }
}

// ---------------------------------------------------------------------------
// 128x128 GEMM tile: C += A(128xK)*B(128xK)^T, bf16 sources, fp32 acc.
// Double-buffered XOR-swizzled LDS; 16x16x32 MFMA; 2x2 waves of 64x64.
// Optional per-A-row mask: keep row iff (sm[row]>0.5) == (pol!=0); sm==null
// keeps all. Masked rows staged as zero (exact s/(1-s) gating for s in {0,1}).
// ---------------------------------------------------------------------------
__device__ __forceinline__ void gemm_bf16(
    const bf16* __restrict__ A, int lda,
    const bf16* __restrict__ B, int ldb,
    int nChunks, short* ls, f32x4 acc[4][4],
    const float* __restrict__ smk, int pol)
{
  const int tid  = threadIdx.x;
  const int lane = tid & 63;
  const int wave = tid >> 6;
  const int wr = (wave & 1) * 64;
  const int wc = (wave >> 1) * 64;
  const int m  = lane & 15;
  const int kg = lane >> 4;

  int srow[4], sseg[4], ssw[4];
  bool keep[4];
#pragma unroll
  for (int i = 0; i < 4; ++i) {
    int linear = i * 256 + tid;
    srow[i] = linear >> 3;
    sseg[i] = linear & 7;
    ssw[i]  = (sseg[i] ^ (srow[i] & 7)) * 8;
    keep[i] = (smk == nullptr) || ((smk[srow[i]] > 0.5f) == (pol != 0));
  }

  const short8 zz = {};
  short8 areg[4], breg[4];
#pragma unroll
  for (int i = 0; i < 4; ++i) {
    areg[i] = keep[i] ? *(const short8*)(A + (size_t)srow[i] * lda + sseg[i] * 8) : zz;
    breg[i] = *(const short8*)(B + (size_t)srow[i] * ldb + sseg[i] * 8);
  }
#pragma unroll
  for (int i = 0; i < 4; ++i) {
    *(short8*)(ls + srow[i] * 64 + ssw[i])        = areg[i];
    *(short8*)(ls + 8192 + srow[i] * 64 + ssw[i]) = breg[i];
  }
  __syncthreads();

  for (int c = 0; c < nChunks; ++c) {
    if (c + 1 < nChunks) {
#pragma unroll
      for (int i = 0; i < 4; ++i) {
        areg[i] = keep[i] ? *(const short8*)(A + (size_t)srow[i] * lda + (c + 1) * 64 + sseg[i] * 8) : zz;
        breg[i] = *(const short8*)(B + (size_t)srow[i] * ldb + (c + 1) * 64 + sseg[i] * 8);
      }
    }
    const short* la = ls + (c & 1) * 16384;
    const short* lb = la + 8192;
#pragma unroll
    for (int ks = 0; ks < 2; ++ks) {
      short8 af[4], bfr[4];
#pragma unroll
      for (int f = 0; f < 4; ++f) {
        int ar = wr + f * 16 + m;
        af[f]  = *(const short8*)(la + ar * 64 + (((ks * 4 + kg) ^ (ar & 7)) * 8));
        int br = wc + f * 16 + m;
        bfr[f] = *(const short8*)(lb + br * 64 + (((ks * 4 + kg) ^ (br & 7)) * 8));
      }
#pragma unroll
      for (int fr = 0; fr < 4; ++fr)
#pragma unroll
        for (int fc = 0; fc < 4; ++fc)
          acc[fr][fc] = __builtin_amdgcn_mfma_f32_16x16x32_bf16(af[fr], bfr[fc], acc[fr][fc], 0, 0, 0);
    }
    if (c + 1 < nChunks) {
      short* lw = ls + ((c + 1) & 1) * 16384;
#pragma unroll
      for (int i = 0; i < 4; ++i) {
        *(short8*)(lw + srow[i] * 64 + ssw[i])        = areg[i];
        *(short8*)(lw + 8192 + srow[i] * 64 + ssw[i]) = breg[i];
      }
    }
    __syncthreads();
  }
}

// C/D frag layout (m89/m91-verified): col = lane&15, row = (lane>>4)*4 + reg.
template <typename F>
__device__ __forceinline__ void epilogue(const f32x4 acc[4][4], F&& body)
{
  const int tid = threadIdx.x, lane = tid & 63, wave = tid >> 6;
  const int m = lane & 15, kg = lane >> 4;
  const int wr = (wave & 1) * 64, wc = (wave >> 1) * 64;
#pragma unroll
  for (int fr = 0; fr < 4; ++fr)
#pragma unroll
    for (int fc = 0; fc < 4; ++fc)
#pragma unroll
      for (int r = 0; r < 4; ++r)
        body(wr + fr * 16 + kg * 4 + r, wc + fc * 16 + m, acc[fr][fc][r]);
}

// ---------------------------------------------------------------------------
__global__ void k_diag(float* __restrict__ out, float val)
{
  if (threadIdx.x == 0 && blockIdx.x == 0) out[0] = val;
}

// u[h]=sum_m vs[m]*Wsi[m,h]; w[h]=sum_m vs[m]*Wsh[m,h]; cbd=b_bd.vs (fp64)
__global__ void k_uw(const float* __restrict__ Wsi, const float* __restrict__ Wsh,
                     const float* __restrict__ bbd, const float* __restrict__ vs,
                     double* __restrict__ u, double* __restrict__ wv,
                     double* __restrict__ cbdp)
{
  const int blk = blockIdx.x;
  if (blk < 8) {
    const float* W = (blk < 4) ? Wsi : Wsh;
    double* out = (blk < 4) ? u : wv;
    int h = (blk & 3) * 256 + threadIdx.x;
    double a = 0.0;
    for (int mm = 0; mm < 512; ++mm)
      a += (double)vs[mm] * (double)W[mm * 1024 + h];
    out[h] = a;
  } else if (threadIdx.x < 64) {
    double a = 0.0;
    for (int mm = threadIdx.x; mm < 512; mm += 64)
      a += (double)vs[mm] * (double)bbd[mm];
#pragma unroll
    for (int o = 32; o > 0; o >>= 1) a += __shfl_down(a, o, 64);
    if (threadIdx.x == 0) cbdp[0] = a;
  }
}

// weight split: m0 = w1hh -> hi+lo; m1 = w2ih -> hi; m2 = w2hh -> hi
__global__ void k_wsplit(const float* __restrict__ w1hh, const float* __restrict__ w2ih,
                         const float* __restrict__ w2hh,
                         bf16* __restrict__ o1hh_h, bf16* __restrict__ o1hh_l,
                         bf16* __restrict__ o2ih_h, bf16* __restrict__ o2hh_h)
{
  const int m = blockIdx.x >> 12;
  const size_t i4 = (size_t)(blockIdx.x & 4095) * 256 + threadIdx.x;
  const float* src = (m == 0) ? w1hh : (m == 1) ? w2ih : w2hh;
  bf16* dh = (m == 0) ? o1hh_h : (m == 1) ? o2ih_h : o2hh_h;
  bf16* dl = (m == 0) ? o1hh_l : nullptr;
  f32x4 v = *(const f32x4*)(src + i4 * 4);
  short4v hv, lv;
#pragma unroll
  for (int j = 0; j < 4; ++j) {
    float x = v[j];
    bf16 h = __float2bfloat16(x);
    hv[j] = __builtin_bit_cast(short, h);
    lv[j] = bfbits(x - __bfloat162float(h));
  }
  *(short4v*)((short*)dh + i4 * 4) = hv;
  if (dl) *(short4v*)((short*)dl + i4 * 4) = lv;
}

// ---------------------------------------------------------------------------
// embed (K-split x4): partial[kh] = video(K-range) @ Wemb(K-range)^T, fused
// 3-product split (Ah*Bh + Al*Bh + Ah*Bl), fp32 sources cvt in-kernel.
// Block = (tl 0..7, ct 0..7, kh 0..3); K-range = kh*512..+512 (8 chunks).
// Raw fp32 partial out: Ep[kh][tl*128+row][1024].
// ---------------------------------------------------------------------------
__global__ __launch_bounds__(256, 2) void k_embed(
    const float* __restrict__ video, const float* __restrict__ Wemb,
    float* __restrict__ Ep, int tbase)
{
  __shared__ __align__(16) short ls[32768];   // Ah | Al | Bh | Bl (8192 ea)
  const int tl = blockIdx.x >> 5;
  const int ct = (blockIdx.x >> 2) & 7;
  const int kh = blockIdx.x & 3;
  const int tid = threadIdx.x;

  int srow[4], sseg[4], ssw[4];
  const float* arow[4];
  const float* brow[4];
#pragma unroll
  for (int i = 0; i < 4; ++i) {
    int linear = i * 256 + tid;
    srow[i] = linear >> 3;
    sseg[i] = linear & 7;
    ssw[i]  = (sseg[i] ^ (srow[i] & 7)) * 8;
    arow[i] = video + (size_t)(srow[i] * 64 + tbase + tl) * 2048 + kh * 512 + sseg[i] * 8;
    brow[i] = Wemb + (size_t)(ct * 128 + srow[i]) * 2048 + kh * 512 + sseg[i] * 8;
  }

  f32x4 acc[4][4] = {};
  const int lane = tid & 63, wave = tid >> 6;
  const int wr = (wave & 1) * 64, wc = (wave >> 1) * 64;
  const int m = lane & 15, kg = lane >> 4;

  short8 ah[4], al[4], bh[4], bl[4];
#pragma unroll
  for (int i = 0; i < 4; ++i) {
    cvt8hl(arow[i], ah[i], al[i]);
    cvt8hl(brow[i], bh[i], bl[i]);
  }
#pragma unroll
  for (int i = 0; i < 4; ++i) {
    *(short8*)(ls +         srow[i] * 64 + ssw[i]) = ah[i];
    *(short8*)(ls +  8192 + srow[i] * 64 + ssw[i]) = al[i];
    *(short8*)(ls + 16384 + srow[i] * 64 + ssw[i]) = bh[i];
    *(short8*)(ls + 24576 + srow[i] * 64 + ssw[i]) = bl[i];
  }
  __syncthreads();

  for (int c = 0; c < 8; ++c) {
    if (c + 1 < 8) {
#pragma unroll
      for (int i = 0; i < 4; ++i) {
        cvt8hl(arow[i] + (c + 1) * 64, ah[i], al[i]);
        cvt8hl(brow[i] + (c + 1) * 64, bh[i], bl[i]);
      }
    }
#pragma unroll
    for (int ks = 0; ks < 2; ++ks) {
      short8 afh[4], afl[4], bfh[4], bfl[4];
      int asw[4], bsw[4];
#pragma unroll
      for (int f = 0; f < 4; ++f) {
        int ar = wr + f * 16 + m;
        asw[f] = ar * 64 + (((ks * 4 + kg) ^ (ar & 7)) * 8);
        int br = wc + f * 16 + m;
        bsw[f] = br * 64 + (((ks * 4 + kg) ^ (br & 7)) * 8);
        afh[f] = *(const short8*)(ls +         asw[f]);
        bfh[f] = *(const short8*)(ls + 16384 + bsw[f]);
      }
#pragma unroll
      for (int fr = 0; fr < 4; ++fr)
#pragma unroll
        for (int fc = 0; fc < 4; ++fc)
          acc[fr][fc] = __builtin_amdgcn_mfma_f32_16x16x32_bf16(afh[fr], bfh[fc], acc[fr][fc], 0, 0, 0);
#pragma unroll
      for (int f = 0; f < 4; ++f)
        afl[f] = *(const short8*)(ls + 8192 + asw[f]);
#pragma unroll
      for (int fr = 0; fr < 4; ++fr)
#pragma unroll
        for (int fc = 0; fc < 4; ++fc)
          acc[fr][fc] = __builtin_amdgcn_mfma_f32_16x16x32_bf16(afl[fr], bfh[fc], acc[fr][fc], 0, 0, 0);
#pragma unroll
      for (int f = 0; f < 4; ++f)
        bfl[f] = *(const short8*)(ls + 24576 + bsw[f]);
#pragma unroll
      for (int fr = 0; fr < 4; ++fr)
#pragma unroll
        for (int fc = 0; fc < 4; ++fc)
          acc[fr][fc] = __builtin_amdgcn_mfma_f32_16x16x32_bf16(afh[fr], bfl[fc], acc[fr][fc], 0, 0, 0);
    }
    if (c + 1 < 8) {
      __syncthreads();
#pragma unroll
      for (int i = 0; i < 4; ++i) {
        *(short8*)(ls +         srow[i] * 64 + ssw[i]) = ah[i];
        *(short8*)(ls +  8192 + srow[i] * 64 + ssw[i]) = al[i];
        *(short8*)(ls + 16384 + srow[i] * 64 + ssw[i]) = bh[i];
        *(short8*)(ls + 24576 + srow[i] * 64 + ssw[i]) = bl[i];
      }
      __syncthreads();
    }
  }

  epilogue(acc, [&](int lrow, int lcol, float aval) {
    Ep[(size_t)kh * 1048576 + (size_t)(tl * 128 + lrow) * 1024 + ct * 128 + lcol] = aval;
  });
}

// sum 4 K-partials + bias, relu, split -> v ring (slot-linear: dest elem = e)
__global__ void k_efin(const float* __restrict__ Ep, const float* __restrict__ bemb,
                       bf16* __restrict__ vhi, bf16* __restrict__ vlo)
{
  const size_t e = ((size_t)blockIdx.x * 256 + threadIdx.x) * 4;
  f32x4 a0 = *(const f32x4*)(Ep + e);
  f32x4 a1 = *(const f32x4*)(Ep + 1048576 + e);
  f32x4 a2 = *(const f32x4*)(Ep + 2097152 + e);
  f32x4 a3 = *(const f32x4*)(Ep + 3145728 + e);
  f32x4 bb = *(const f32x4*)(bemb + (e & 1023));
  short4v hv, lv;
#pragma unroll
  for (int j = 0; j < 4; ++j) {
    float x = a0[j] + a1[j] + a2[j] + a3[j] + bb[j];
    x = fmaxf(x, 0.0f);
    bf16 h = __float2bfloat16(x);
    hv[j] = __builtin_bit_cast(short, h);
    lv[j] = bfbits(x - __bfloat162float(h));
  }
  *(short4v*)((short*)vhi + e) = hv;
  *(short4v*)((short*)vlo + e) = lv;
}

// ---------------------------------------------------------------------------
// xgates: Gx[rt] = vh@W1ih_h + vl@W1ih_h + vh@W1ih_l for 8 t-slots.
// A = v ring (bf16 hi/lo, pre-split); B = W1ih fp32 cvt in-kernel.
// Block map: x=bid&7 (XCD), s=bid>>3; ct = x*4+(s&3), rt = s>>2 — the 8 rt
// blocks sharing a ct land on one XCD so the W1ih slice is fetched once.
// ---------------------------------------------------------------------------
__global__ __launch_bounds__(256, 2) void k_xgates(
    const bf16* __restrict__ vhi, const bf16* __restrict__ vlo,
    const float* __restrict__ Wih1, float* __restrict__ Gx)
{
  __shared__ __align__(16) short ls[32768];   // Ah | Al | Bh | Bl
  const int x  = blockIdx.x & 7;
  const int s  = blockIdx.x >> 3;
  const int ct = x * 4 + (s & 3);
  const int rt = s >> 2;
  const int tid = threadIdx.x;

  int srow[4], sseg[4], ssw[4];
  const bf16* arh[4];
  const bf16* arl[4];
  const float* brow[4];
#pragma unroll
  for (int i = 0; i < 4; ++i) {
    int linear = i * 256 + tid;
    srow[i] = linear >> 3;
    sseg[i] = linear & 7;
    ssw[i]  = (sseg[i] ^ (srow[i] & 7)) * 8;
    arh[i] = vhi + (size_t)rt * 131072 + (size_t)srow[i] * 1024 + sseg[i] * 8;
    arl[i] = vlo + (size_t)rt * 131072 + (size_t)srow[i] * 1024 + sseg[i] * 8;
    brow[i] = Wih1 + (size_t)(ct * 128 + srow[i]) * 1024 + sseg[i] * 8;
  }

  f32x4 acc[4][4] = {};
  const int lane = tid & 63, wave = tid >> 6;
  const int wr = (wave & 1) * 64, wc = (wave >> 1) * 64;
  const int m = lane & 15, kg = lane >> 4;

  short8 ah[4], al[4], bh[4], bl[4];
#pragma unroll
  for (int i = 0; i < 4; ++i) {
    ah[i] = *(const short8*)(arh[i]);
    al[i] = *(const short8*)(arl[i]);
    cvt8hl(brow[i], bh[i], bl[i]);
  }
#pragma unroll
  for (int i = 0; i < 4; ++i) {
    *(short8*)(ls +         srow[i] * 64 + ssw[i]) = ah[i];
    *(short8*)(ls +  8192 + srow[i] * 64 + ssw[i]) = al[i];
    *(short8*)(ls + 16384 + srow[i] * 64 + ssw[i]) = bh[i];
    *(short8*)(ls + 24576 + srow[i] * 64 + ssw[i]) = bl[i];
  }
  __syncthreads();

  for (int c = 0; c < 16; ++c) {
    if (c + 1 < 16) {
#pragma unroll
      for (int i = 0; i < 4; ++i) {
        ah[i] = *(const short8*)(arh[i] + (c + 1) * 64);
        al[i] = *(const short8*)(arl[i] + (c + 1) * 64);
        cvt8hl(brow[i] + (c + 1) * 64, bh[i], bl[i]);
      }
    }
#pragma unroll
    for (int ks = 0; ks < 2; ++ks) {
      short8 afh[4], afl[4], bfh[4], bfl[4];
      int asw[4], bsw[4];
#pragma unroll
      for (int f = 0; f < 4; ++f) {
        int ar = wr + f * 16 + m;
        asw[f] = ar * 64 + (((ks * 4 + kg) ^ (ar & 7)) * 8);
        int br = wc + f * 16 + m;
        bsw[f] = br * 64 + (((ks * 4 + kg) ^ (br & 7)) * 8);
        afh[f] = *(const short8*)(ls +         asw[f]);
        bfh[f] = *(const short8*)(ls + 16384 + bsw[f]);
      }
#pragma unroll
      for (int fr = 0; fr < 4; ++fr)
#pragma unroll
        for (int fc = 0; fc < 4; ++fc)
          acc[fr][fc] = __builtin_amdgcn_mfma_f32_16x16x32_bf16(afh[fr], bfh[fc], acc[fr][fc], 0, 0, 0);
#pragma unroll
      for (int f = 0; f < 4; ++f)
        afl[f] = *(const short8*)(ls + 8192 + asw[f]);
#pragma unroll
      for (int fr = 0; fr < 4; ++fr)
#pragma unroll
        for (int fc = 0; fc < 4; ++fc)
          acc[fr][fc] = __builtin_amdgcn_mfma_f32_16x16x32_bf16(afl[fr], bfh[fc], acc[fr][fc], 0, 0, 0);
#pragma unroll
      for (int f = 0; f < 4; ++f)
        bfl[f] = *(const short8*)(ls + 24576 + bsw[f]);
#pragma unroll
      for (int fr = 0; fr < 4; ++fr)
#pragma unroll
        for (int fc = 0; fc < 4; ++fc)
          acc[fr][fc] = __builtin_amdgcn_mfma_f32_16x16x32_bf16(afh[fr], bfl[fc], acc[fr][fc], 0, 0, 0);
    }
    if (c + 1 < 16) {
      __syncthreads();
#pragma unroll
      for (int i = 0; i < 4; ++i) {
        *(short8*)(ls +         srow[i] * 64 + ssw[i]) = ah[i];
        *(short8*)(ls +  8192 + srow[i] * 64 + ssw[i]) = al[i];
        *(short8*)(ls + 16384 + srow[i] * 64 + ssw[i]) = bh[i];
        *(short8*)(ls + 24576 + srow[i] * 64 + ssw[i]) = bl[i];
      }
      __syncthreads();
    }
  }

  epilogue(acc, [&](int lrow, int lcol, float aval) {
    Gx[(size_t)rt * 524288 + (size_t)lrow * 4096 + ct * 128 + lcol] = aval;
  });
}

// ---------------------------------------------------------------------------
// G_k (h-side): grid 128, unit u = bid>>5, ct = bid&31.
//  u0: h1n*(1-s) @ w1hh_h (hi+lo A) -> P0    u1: h1nh*(1-s) @ w1hh_l -> P1
//  u2: h1n*s     @ w2ih_h (hi+lo A) -> P2    u3: h2 @ w2hh_h (hi+lo A) -> P3
// ---------------------------------------------------------------------------
__global__ __launch_bounds__(256, 2) void k_step(
    const bf16* __restrict__ h1nh, const bf16* __restrict__ h1nl,
    const bf16* __restrict__ h2h, const bf16* __restrict__ h2l,
    const bf16* __restrict__ w1hh_h, const bf16* __restrict__ w1hh_l,
    const bf16* __restrict__ w2ih_h, const bf16* __restrict__ w2hh_h,
    const float* __restrict__ sm, float* __restrict__ R, int k)
{
  __shared__ __align__(16) short ls[32768];
  const int u  = blockIdx.x >> 5;
  const int ct = blockIdx.x & 31;
  if (k == 64 && u < 2) return;   // E_64 only consumes lstm2 partials

  const bf16 *A0, *A1, *B;
  const float* smp = sm;
  int pol = 0;
  switch (u) {
    case 0:  A0 = h1nh; A1 = h1nl;   B = w1hh_h; pol = 0; break;
    case 1:  A0 = h1nh; A1 = nullptr; B = w1hh_l; pol = 0; break;
    case 2:  A0 = h1nh; A1 = h1nl;   B = w2ih_h; pol = 1; break;
    default: A0 = h2h;  A1 = h2l;    B = w2hh_h; smp = nullptr; break;
  }

  f32x4 acc[4][4] = {};
  gemm_bf16(A0, 1024, B + (size_t)ct * 131072, 1024, 16, ls, acc, smp, pol);
  if (A1)
    gemm_bf16(A1, 1024, B + (size_t)ct * 131072, 1024, 16, ls, acc, smp, pol);

  float* Rout = R + (size_t)u * 524288;
  epilogue(acc, [&](int lrow, int lcol, float aval) {
    Rout[(size_t)lrow * 4096 + ct * 128 + lcol] = aval;
  });
}

// ---------------------------------------------------------------------------
// E_k: grid 128 (b = blockIdx), 256 threads, 4 j each.
// Inline zx (fp64 v.u); lstm1 gates = Gx[k&7] + P0 + P1 (k>0) + b1;
// lstm2 gates = P2 + P3. Writes unmasked h1n hi/lo + s mask.
// ---------------------------------------------------------------------------
__global__ void k_elem(const float* __restrict__ R, const float* __restrict__ Gx,
                       const bf16* __restrict__ vhi, const bf16* __restrict__ vlo,
                       const double* __restrict__ uvec, const double* __restrict__ cbdp,
                       float* __restrict__ craw,
                       bf16* __restrict__ h1nh, bf16* __restrict__ h1nl,
                       float* __restrict__ sm,
                       float* __restrict__ c2, bf16* __restrict__ h2h, bf16* __restrict__ h2l,
                       float* __restrict__ rdm, const double* __restrict__ wv,
                       const float* __restrict__ b1, float* __restrict__ dout, int k)
{
  __shared__ double red[4];
  const int tid = threadIdx.x;
  const int b   = blockIdx.x;
  const size_t broff = (size_t)b * 4096;
  const float* P0 = R + broff;
  const float* P1 = P0 + 524288;
  const float* P2 = P0 + 2 * 524288;
  const float* P3 = P0 + 3 * 524288;
  const float* GX = Gx + (size_t)(k & 7) * 524288 + broff;

  if (k < 64) {  // boundary gate + lstm1 step k
    // inline zx: fp64 dot of v row with u
    const bf16* vhr = vhi + (size_t)(k & 7) * 131072 + (size_t)b * 1024;
    const bf16* vlr = vlo + (size_t)(k & 7) * 131072 + (size_t)b * 1024;
    double za = 0.0;
#pragma unroll
    for (int ji = 0; ji < 4; ++ji) {
      int j = tid + ji * 256;
      za += (double)(__bfloat162float(vhr[j]) + __bfloat162float(vlr[j])) * uvec[j];
    }
#pragma unroll
    for (int o = 32; o > 0; o >>= 1) za += __shfl_down(za, o, 64);
    if ((tid & 63) == 0) red[tid >> 6] = za;
    __syncthreads();
    float zpre = (float)(red[0] + red[1] + red[2] + red[3] + cbdp[0]);
    if (k > 0) zpre += rdm[(k - 1) * 128 + b];
    float s  = (sigm(zpre) > 0.5f) ? 1.0f : 0.0f;   // round(): 0.5 -> 0
    float om = 1.0f - s;
    __syncthreads();   // red about to be reused

    double rd = 0.0;
#pragma unroll
    for (int ji = 0; ji < 4; ++ji) {
      int j = tid + ji * 256;
      float gi = GX[j]        + b1[j];
      float gf = GX[1024 + j] + b1[1024 + j];
      float gg = GX[2048 + j] + b1[2048 + j];
      float go = GX[3072 + j] + b1[3072 + j];
      if (k > 0) {
        gi += P0[j]        + P1[j];
        gf += P0[1024 + j] + P1[1024 + j];
        gg += P0[2048 + j] + P1[2048 + j];
        go += P0[3072 + j] + P1[3072 + j];
      }
      float cn = sigm(gf) * craw[b * 1024 + j] + sigm(gi) * tanhf(gg);
      float hn = sigm(go) * tanhf(cn);
      craw[b * 1024 + j] = om * cn;
      bf16 hh = __float2bfloat16(hn);
      h1nh[b * 1024 + j] = hh;
      h1nl[b * 1024 + j] = __float2bfloat16(hn - __bfloat162float(hh));
      rd += (double)hn * wv[j];
    }
#pragma unroll
    for (int o = 32; o > 0; o >>= 1) rd += __shfl_down(rd, o, 64);
    if ((tid & 63) == 0) red[tid >> 6] = rd;
    __syncthreads();
    if (tid == 0) {
      rdm[k * 128 + b] = om * (float)(red[0] + red[1] + red[2] + red[3]);
      sm[b] = s;
    }
  }

  if (k >= 1) {  // lstm2 step k-1 (x pre-masked by s_{k-1} in k_step; bias-free)
#pragma unroll
    for (int ji = 0; ji < 4; ++ji) {
      int j = tid + ji * 256;
      float gi = P2[j]        + P3[j];
      float gf = P2[1024 + j] + P3[1024 + j];
      float gg = P2[2048 + j] + P3[2048 + j];
      float go = P2[3072 + j] + P3[3072 + j];
      float cn = sigm(gf) * c2[b * 1024 + j] + sigm(gi) * tanhf(gg);
      float hn = sigm(go) * tanhf(cn);
      c2[b * 1024 + j] = cn;
      bf16 hh = __float2bfloat16(hn);
      h2h[b * 1024 + j] = hh;
      h2l[b * 1024 + j] = __float2bfloat16(hn - __bfloat162float(hh));
      if (k == 64) dout[b * 1024 + j] = hn;
    }
  }
}

// ---------------------------------------------------------------------------
extern "C" void kernel_launch(void* const* d_in, const int* in_sizes, int n_in,
                              void* d_out, int out_size, void* d_ws, size_t ws_size,
                              hipStream_t stream) {
  const float* video = (const float*)d_in[0];
  const float* Wemb  = (const float*)d_in[1];
  const float* bemb  = (const float*)d_in[2];
  const float* Wih1  = (const float*)d_in[3];
  const float* Whh1  = (const float*)d_in[4];
  const float* b1    = (const float*)d_in[5];
  const float* Wsi   = (const float*)d_in[6];
  const float* Wsh   = (const float*)d_in[7];
  const float* bbd   = (const float*)d_in[8];
  const float* vs    = (const float*)d_in[9];
  const float* Wih2  = (const float*)d_in[10];
  const float* Whh2  = (const float*)d_in[11];
  float* dout = (float*)d_out;

  static const int exp_sizes[12] = {
    128 * 64 * 2048, 1024 * 2048, 1024, 4096 * 1024, 4096 * 1024, 4096,
    512 * 1024, 512 * 1024, 512, 512, 4096 * 1024, 4096 * 1024 };
  int bad = -1;
  if (n_in != 12) bad = 99;
  else if (out_size != 131072) bad = 98;
  else
    for (int i = 0; i < 12; ++i)
      if (in_sizes[i] != exp_sizes[i]) { bad = i; break; }
  if (bad >= 0) {
    k_diag<<<1, 64, 0, stream>>>(dout, 10000.0f + (float)bad);
    return;
  }

  char* ws = (char*)d_ws;
  size_t off = 0;
  auto alloc = [&](size_t bytes) {
    char* p = ws + off;
    off += (bytes + 255) & ~(size_t)255;
    return p;
  };
  // zero region (state), memset each launch
  bf16*  h1nh = (bf16*)alloc(262144);
  bf16*  h1nl = (bf16*)alloc(262144);
  bf16*  h2h  = (bf16*)alloc(262144);
  bf16*  h2l  = (bf16*)alloc(262144);
  float* c2   = (float*)alloc(524288);
  float* craw = (float*)alloc(524288);
  float* sm   = (float*)alloc(512);
  const size_t zeroBytes = off;
  // rest (written before read every launch)
  double* u    = (double*)alloc(8192);
  double* wvv  = (double*)alloc(8192);
  double* cbdp = (double*)alloc(256);
  float* rdm   = (float*)alloc(64 * 128 * 4);
  bf16* w1hh_h = (bf16*)alloc(8388608);
  bf16* w1hh_l = (bf16*)alloc(8388608);
  bf16* w2ih_h = (bf16*)alloc(8388608);
  bf16* w2hh_h = (bf16*)alloc(8388608);
  float* R     = (float*)alloc(4 * 2097152);            // 4 partials, 8.4 MB
  float* Gxf   = (float*)alloc(8 * 2097152);            // Gx ring / embed partials
  bf16* vhi    = (bf16*)alloc(8 * 131072 * 2);          // v ring, 8 slots
  bf16* vlo    = (bf16*)alloc(8 * 131072 * 2);

  if (ws_size < off) {
    k_diag<<<1, 64, 0, stream>>>(dout, 100.0f + (float)(ws_size >> 20));
    return;
  }

  (void)hipMemsetAsync(d_ws, 0, zeroBytes, stream);
  k_uw<<<9, 256, 0, stream>>>(Wsi, Wsh, bbd, vs, u, wvv, cbdp);
  k_wsplit<<<12288, 256, 0, stream>>>(Whh1, Wih2, Whh2,
                                      w1hh_h, w1hh_l, w2ih_h, w2hh_h);

  for (int k = 0; k <= 64; ++k) {
    if (k < 64 && (k & 7) == 0) {
      k_embed<<<256, 256, 0, stream>>>(video, Wemb, Gxf, k);          // Ep alias
      k_efin<<<1024, 256, 0, stream>>>(Gxf, bemb, vhi, vlo);
      k_xgates<<<256, 256, 0, stream>>>(vhi, vlo, Wih1, Gxf);         // writes Gx
    }
    if (k > 0)
      k_step<<<128, 256, 0, stream>>>(h1nh, h1nl, h2h, h2l,
                                      w1hh_h, w1hh_l, w2ih_h, w2hh_h, sm, R, k);
    k_elem<<<128, 256, 0, stream>>>(R, Gxf, vhi, vlo, u, cbdp, craw,
                                    h1nh, h1nl, sm, c2, h2h, h2l,
                                    rdm, wvv, b1, dout, k);
  }
}

// Round 4
// 2690.925 us; speedup vs baseline: 1.2623x; 1.2623x over previous
//
#include <hip/hip_runtime.h>
#include <hip/hip_bf16.h>
#include <math.h>

// EncoderRNN on MI355X. Inputs fp32, output fp32.
// R15 = R14 pipeline, hardened: single gemm3/gemm2 call sites in k_step
// (halves inlined MFMA bodies / compile time). Structure:
// All tile-GEMMs use fused-product staging (stage Ah|Al|Bh[|Bl] once per
// K-chunk, issue 2-3 MFMA products), 128 KB double-buffered LDS, depth-2
// load issue (write c+1 / issue c+2 / compute c / one barrier). fp32 sources
// convert at LDS-write time. k_step: 4 jobs x 32 ct = 128 blocks, 4 partials:
//   P0/P1 = h1n(1-s) @ w1hh (3-product split, K-halves)
//   P2    = h1n*s    @ w2ih_h (2-product)      P3 = h2 @ w2hh_h (2-product)
// k_elem (512 thr): inline fp64 zx dot; lstm1 = Gx+P0+P1+b1; lstm2 = P2+P3.
// Embed path per 8 steps: k_embed (256 blk, K-split x4, dbuf) -> Ep (alias
// Gxf) -> k_efin -> k_xgates (256 blk, dbuf, W1ih fp32 cvt-at-store) -> Gx.

typedef __attribute__((ext_vector_type(8))) short short8;
typedef __attribute__((ext_vector_type(4))) short short4v;
typedef __attribute__((ext_vector_type(4))) float f32x4;
typedef __hip_bfloat16 bf16;

__device__ __forceinline__ float sigm(float x) { return 1.0f / (1.0f + expf(-x)); }
__device__ __forceinline__ short bfbits(float x) {
  bf16 h = __float2bfloat16(x);
  return __builtin_bit_cast(short, h);
}
// two f32x4 (regs) -> bf16 hi + residual lo
__device__ __forceinline__ void cvtfp(const f32x4 a, const f32x4 b,
                                      short8& hi, short8& lo)
{
#pragma unroll
  for (int j = 0; j < 8; ++j) {
    float x = (j < 4) ? a[j] : b[j - 4];
    bf16 h = __float2bfloat16(x);
    hi[j] = __builtin_bit_cast(short, h);
    lo[j] = bfbits(x - __bfloat162float(h));
  }
}

// LDS geometry: tile = 128x64 bf16 = 8192 shorts. Buffer = 4 tiles = 32768
// shorts (64 KB). Double buffer = 65536 shorts (128 KB). XOR-swizzled.
#define TILE 8192
#define BUF  32768

// staging indices (row/seg/swizzled-offset) for 256 threads x 4 iters
#define STAGE_IDX                                              \
  int srow[4], sseg[4], ssw[4];                                \
  _Pragma("unroll")                                            \
  for (int i = 0; i < 4; ++i) {                                \
    int linear = i * 256 + threadIdx.x;                        \
    srow[i] = linear >> 3;                                     \
    sseg[i] = linear & 7;                                      \
    ssw[i]  = (sseg[i] ^ (srow[i] & 7)) * 8;                   \
  }

// MFMA fragment constants
#define FRAG_IDX                                               \
  const int lane = threadIdx.x & 63, wave = threadIdx.x >> 6;  \
  const int wr = (wave & 1) * 64, wc = (wave >> 1) * 64;       \
  const int m = lane & 15, kg = lane >> 4;

// ---------------------------------------------------------------------------
// gemm3: acc += Ah@Bh^T + Al@Bh^T + Ah@Bl^T over nChunks K-chunks of 64.
// A row-major [128][1024] (pre-offset), B row-major [128][1024] (pre-offset).
// Optional A-row mask: keep iff (smk[row]>0.5)==(pol!=0).
// ---------------------------------------------------------------------------
__device__ __forceinline__ void gemm3(
    const bf16* __restrict__ Ah, const bf16* __restrict__ Al,
    const bf16* __restrict__ Bh, const bf16* __restrict__ Bl,
    int nChunks, const float* __restrict__ smk, int pol,
    short* ls, f32x4 acc[4][4])
{
  STAGE_IDX
  FRAG_IDX
  bool keep[4];
#pragma unroll
  for (int i = 0; i < 4; ++i)
    keep[i] = (smk == nullptr) || ((smk[srow[i]] > 0.5f) == (pol != 0));

  const short8 zz = {};
  short8 rah[4], ral[4], rbh[4], rbl[4];

  auto LOAD = [&](int c) {
#pragma unroll
    for (int i = 0; i < 4; ++i) {
      size_t o = (size_t)srow[i] * 1024 + c * 64 + sseg[i] * 8;
      rah[i] = keep[i] ? *(const short8*)(Ah + o) : zz;
      ral[i] = keep[i] ? *(const short8*)(Al + o) : zz;
      rbh[i] = *(const short8*)(Bh + o);
      rbl[i] = *(const short8*)(Bl + o);
    }
  };
  auto STORE = [&](int buf) {
    short* p = ls + buf * BUF;
#pragma unroll
    for (int i = 0; i < 4; ++i) {
      int o = srow[i] * 64 + ssw[i];
      *(short8*)(p + o)            = rah[i];
      *(short8*)(p + TILE + o)     = ral[i];
      *(short8*)(p + 2 * TILE + o) = rbh[i];
      *(short8*)(p + 3 * TILE + o) = rbl[i];
    }
  };

  LOAD(0); STORE(0);
  if (nChunks > 1) LOAD(1);
  __syncthreads();

  for (int c = 0; c < nChunks; ++c) {
    if (c + 1 < nChunks) STORE((c + 1) & 1);
    if (c + 2 < nChunks) LOAD(c + 2);
    const short* la = ls + (c & 1) * BUF;
#pragma unroll
    for (int ks = 0; ks < 2; ++ks) {
      short8 afh[4], afl[4], bfh[4], bfl[4];
      int asw[4], bsw[4];
#pragma unroll
      for (int f = 0; f < 4; ++f) {
        int ar = wr + f * 16 + m;
        asw[f] = ar * 64 + (((ks * 4 + kg) ^ (ar & 7)) * 8);
        int br = wc + f * 16 + m;
        bsw[f] = br * 64 + (((ks * 4 + kg) ^ (br & 7)) * 8);
        afh[f] = *(const short8*)(la + asw[f]);
        bfh[f] = *(const short8*)(la + 2 * TILE + bsw[f]);
      }
#pragma unroll
      for (int fr = 0; fr < 4; ++fr)
#pragma unroll
        for (int fc = 0; fc < 4; ++fc)
          acc[fr][fc] = __builtin_amdgcn_mfma_f32_16x16x32_bf16(afh[fr], bfh[fc], acc[fr][fc], 0, 0, 0);
#pragma unroll
      for (int f = 0; f < 4; ++f)
        afl[f] = *(const short8*)(la + TILE + asw[f]);
#pragma unroll
      for (int fr = 0; fr < 4; ++fr)
#pragma unroll
        for (int fc = 0; fc < 4; ++fc)
          acc[fr][fc] = __builtin_amdgcn_mfma_f32_16x16x32_bf16(afl[fr], bfh[fc], acc[fr][fc], 0, 0, 0);
#pragma unroll
      for (int f = 0; f < 4; ++f)
        bfl[f] = *(const short8*)(la + 3 * TILE + bsw[f]);
#pragma unroll
      for (int fr = 0; fr < 4; ++fr)
#pragma unroll
        for (int fc = 0; fc < 4; ++fc)
          acc[fr][fc] = __builtin_amdgcn_mfma_f32_16x16x32_bf16(afh[fr], bfl[fc], acc[fr][fc], 0, 0, 0);
    }
    if (c + 1 < nChunks) __syncthreads();
  }
}

// ---------------------------------------------------------------------------
// gemm2: acc += Ah@B^T + Al@B^T (B hi-only).
// ---------------------------------------------------------------------------
__device__ __forceinline__ void gemm2(
    const bf16* __restrict__ Ah, const bf16* __restrict__ Al,
    const bf16* __restrict__ B,
    int nChunks, const float* __restrict__ smk, int pol,
    short* ls, f32x4 acc[4][4])
{
  STAGE_IDX
  FRAG_IDX
  bool keep[4];
#pragma unroll
  for (int i = 0; i < 4; ++i)
    keep[i] = (smk == nullptr) || ((smk[srow[i]] > 0.5f) == (pol != 0));

  const short8 zz = {};
  short8 rah[4], ral[4], rb[4];

  auto LOAD = [&](int c) {
#pragma unroll
    for (int i = 0; i < 4; ++i) {
      size_t o = (size_t)srow[i] * 1024 + c * 64 + sseg[i] * 8;
      rah[i] = keep[i] ? *(const short8*)(Ah + o) : zz;
      ral[i] = keep[i] ? *(const short8*)(Al + o) : zz;
      rb[i]  = *(const short8*)(B + o);
    }
  };
  auto STORE = [&](int buf) {
    short* p = ls + buf * BUF;
#pragma unroll
    for (int i = 0; i < 4; ++i) {
      int o = srow[i] * 64 + ssw[i];
      *(short8*)(p + o)            = rah[i];
      *(short8*)(p + TILE + o)     = ral[i];
      *(short8*)(p + 2 * TILE + o) = rb[i];
    }
  };

  LOAD(0); STORE(0);
  if (nChunks > 1) LOAD(1);
  __syncthreads();

  for (int c = 0; c < nChunks; ++c) {
    if (c + 1 < nChunks) STORE((c + 1) & 1);
    if (c + 2 < nChunks) LOAD(c + 2);
    const short* la = ls + (c & 1) * BUF;
#pragma unroll
    for (int ks = 0; ks < 2; ++ks) {
      short8 afh[4], afl[4], bf[4];
      int asw[4], bsw[4];
#pragma unroll
      for (int f = 0; f < 4; ++f) {
        int ar = wr + f * 16 + m;
        asw[f] = ar * 64 + (((ks * 4 + kg) ^ (ar & 7)) * 8);
        int br = wc + f * 16 + m;
        bsw[f] = br * 64 + (((ks * 4 + kg) ^ (br & 7)) * 8);
        afh[f] = *(const short8*)(la + asw[f]);
        bf[f]  = *(const short8*)(la + 2 * TILE + bsw[f]);
      }
#pragma unroll
      for (int fr = 0; fr < 4; ++fr)
#pragma unroll
        for (int fc = 0; fc < 4; ++fc)
          acc[fr][fc] = __builtin_amdgcn_mfma_f32_16x16x32_bf16(afh[fr], bf[fc], acc[fr][fc], 0, 0, 0);
#pragma unroll
      for (int f = 0; f < 4; ++f)
        afl[f] = *(const short8*)(la + TILE + asw[f]);
#pragma unroll
      for (int fr = 0; fr < 4; ++fr)
#pragma unroll
        for (int fc = 0; fc < 4; ++fc)
          acc[fr][fc] = __builtin_amdgcn_mfma_f32_16x16x32_bf16(afl[fr], bf[fc], acc[fr][fc], 0, 0, 0);
    }
    if (c + 1 < nChunks) __syncthreads();
  }
}

// C/D frag layout (m89/m91-verified): col = lane&15, row = (lane>>4)*4 + reg.
template <typename F>
__device__ __forceinline__ void epilogue(const f32x4 acc[4][4], F&& body)
{
  FRAG_IDX
#pragma unroll
  for (int fr = 0; fr < 4; ++fr)
#pragma unroll
    for (int fc = 0; fc < 4; ++fc)
#pragma unroll
      for (int r = 0; r < 4; ++r)
        body(wr + fr * 16 + kg * 4 + r, wc + fc * 16 + m, acc[fr][fc][r]);
}

// ---------------------------------------------------------------------------
__global__ void k_diag(float* __restrict__ out, float val)
{
  if (threadIdx.x == 0 && blockIdx.x == 0) out[0] = val;
}

// u[h]=sum_m vs[m]*Wsi[m,h]; w[h]=sum_m vs[m]*Wsh[m,h]; cbd=b_bd.vs (fp64)
__global__ void k_uw(const float* __restrict__ Wsi, const float* __restrict__ Wsh,
                     const float* __restrict__ bbd, const float* __restrict__ vs,
                     double* __restrict__ u, double* __restrict__ wv,
                     double* __restrict__ cbdp)
{
  const int blk = blockIdx.x;
  if (blk < 8) {
    const float* W = (blk < 4) ? Wsi : Wsh;
    double* out = (blk < 4) ? u : wv;
    int h = (blk & 3) * 256 + threadIdx.x;
    double a = 0.0;
    for (int mm = 0; mm < 512; ++mm)
      a += (double)vs[mm] * (double)W[mm * 1024 + h];
    out[h] = a;
  } else if (threadIdx.x < 64) {
    double a = 0.0;
    for (int mm = threadIdx.x; mm < 512; mm += 64)
      a += (double)vs[mm] * (double)bbd[mm];
#pragma unroll
    for (int o = 32; o > 0; o >>= 1) a += __shfl_down(a, o, 64);
    if (threadIdx.x == 0) cbdp[0] = a;
  }
}

// weight split: m0 = w1hh -> hi+lo; m1 = w2ih -> hi; m2 = w2hh -> hi
__global__ void k_wsplit(const float* __restrict__ w1hh, const float* __restrict__ w2ih,
                         const float* __restrict__ w2hh,
                         bf16* __restrict__ o1hh_h, bf16* __restrict__ o1hh_l,
                         bf16* __restrict__ o2ih_h, bf16* __restrict__ o2hh_h)
{
  const int m = blockIdx.x >> 12;
  const size_t i4 = (size_t)(blockIdx.x & 4095) * 256 + threadIdx.x;
  const float* src = (m == 0) ? w1hh : (m == 1) ? w2ih : w2hh;
  bf16* dh = (m == 0) ? o1hh_h : (m == 1) ? o2ih_h : o2hh_h;
  bf16* dl = (m == 0) ? o1hh_l : nullptr;
  f32x4 v = *(const f32x4*)(src + i4 * 4);
  short4v hv, lv;
#pragma unroll
  for (int j = 0; j < 4; ++j) {
    float x = v[j];
    bf16 h = __float2bfloat16(x);
    hv[j] = __builtin_bit_cast(short, h);
    lv[j] = bfbits(x - __bfloat162float(h));
  }
  *(short4v*)((short*)dh + i4 * 4) = hv;
  if (dl) *(short4v*)((short*)dl + i4 * 4) = lv;
}

// ---------------------------------------------------------------------------
// embed (K-split x4, dbuf): Ep[kh] += video(Krange) @ Wemb(Krange)^T with the
// fused 3-product split. fp32 loads staged raw in regs; cvt at LDS-write.
// Block = (tl 0..7, ct 0..7, kh 0..3); 8 chunks.
// ---------------------------------------------------------------------------
__global__ __launch_bounds__(256, 1) void k_embed(
    const float* __restrict__ video, const float* __restrict__ Wemb,
    float* __restrict__ Ep, int tbase)
{
  __shared__ __align__(16) short ls[65536];
  const int tl = blockIdx.x >> 5;
  const int ct = (blockIdx.x >> 2) & 7;
  const int kh = blockIdx.x & 3;

  STAGE_IDX
  FRAG_IDX
  const float* arow[4];
  const float* brow[4];
#pragma unroll
  for (int i = 0; i < 4; ++i) {
    arow[i] = video + (size_t)(srow[i] * 64 + tbase + tl) * 2048 + kh * 512 + sseg[i] * 8;
    brow[i] = Wemb + (size_t)(ct * 128 + srow[i]) * 2048 + kh * 512 + sseg[i] * 8;
  }

  f32x4 fa[4][2], fb[4][2];
  auto LOAD = [&](int c) {
#pragma unroll
    for (int i = 0; i < 4; ++i) {
      fa[i][0] = *(const f32x4*)(arow[i] + c * 64);
      fa[i][1] = *(const f32x4*)(arow[i] + c * 64 + 4);
      fb[i][0] = *(const f32x4*)(brow[i] + c * 64);
      fb[i][1] = *(const f32x4*)(brow[i] + c * 64 + 4);
    }
  };
  auto STORE = [&](int buf) {
    short* p = ls + buf * BUF;
#pragma unroll
    for (int i = 0; i < 4; ++i) {
      short8 hi, lo;
      int o = srow[i] * 64 + ssw[i];
      cvtfp(fa[i][0], fa[i][1], hi, lo);
      *(short8*)(p + o)        = hi;
      *(short8*)(p + TILE + o) = lo;
      cvtfp(fb[i][0], fb[i][1], hi, lo);
      *(short8*)(p + 2 * TILE + o) = hi;
      *(short8*)(p + 3 * TILE + o) = lo;
    }
  };

  f32x4 acc[4][4] = {};
  LOAD(0); STORE(0);
  LOAD(1);
  __syncthreads();

  for (int c = 0; c < 8; ++c) {
    if (c + 1 < 8) STORE((c + 1) & 1);
    if (c + 2 < 8) LOAD(c + 2);
    const short* la = ls + (c & 1) * BUF;
#pragma unroll
    for (int ks = 0; ks < 2; ++ks) {
      short8 afh[4], afl[4], bfh[4], bfl[4];
      int asw[4], bsw[4];
#pragma unroll
      for (int f = 0; f < 4; ++f) {
        int ar = wr + f * 16 + m;
        asw[f] = ar * 64 + (((ks * 4 + kg) ^ (ar & 7)) * 8);
        int br = wc + f * 16 + m;
        bsw[f] = br * 64 + (((ks * 4 + kg) ^ (br & 7)) * 8);
        afh[f] = *(const short8*)(la + asw[f]);
        bfh[f] = *(const short8*)(la + 2 * TILE + bsw[f]);
      }
#pragma unroll
      for (int fr = 0; fr < 4; ++fr)
#pragma unroll
        for (int fc = 0; fc < 4; ++fc)
          acc[fr][fc] = __builtin_amdgcn_mfma_f32_16x16x32_bf16(afh[fr], bfh[fc], acc[fr][fc], 0, 0, 0);
#pragma unroll
      for (int f = 0; f < 4; ++f)
        afl[f] = *(const short8*)(la + TILE + asw[f]);
#pragma unroll
      for (int fr = 0; fr < 4; ++fr)
#pragma unroll
        for (int fc = 0; fc < 4; ++fc)
          acc[fr][fc] = __builtin_amdgcn_mfma_f32_16x16x32_bf16(afl[fr], bfh[fc], acc[fr][fc], 0, 0, 0);
#pragma unroll
      for (int f = 0; f < 4; ++f)
        bfl[f] = *(const short8*)(la + 3 * TILE + bsw[f]);
#pragma unroll
      for (int fr = 0; fr < 4; ++fr)
#pragma unroll
        for (int fc = 0; fc < 4; ++fc)
          acc[fr][fc] = __builtin_amdgcn_mfma_f32_16x16x32_bf16(afh[fr], bfl[fc], acc[fr][fc], 0, 0, 0);
    }
    if (c + 1 < 8) __syncthreads();
  }

  epilogue(acc, [&](int lrow, int lcol, float aval) {
    Ep[(size_t)kh * 1048576 + (size_t)(tl * 128 + lrow) * 1024 + ct * 128 + lcol] = aval;
  });
}

// sum 4 K-partials + bias, relu, split -> v ring (slot-linear)
__global__ void k_efin(const float* __restrict__ Ep, const float* __restrict__ bemb,
                       bf16* __restrict__ vhi, bf16* __restrict__ vlo)
{
  const size_t e = ((size_t)blockIdx.x * 256 + threadIdx.x) * 4;
  f32x4 a0 = *(const f32x4*)(Ep + e);
  f32x4 a1 = *(const f32x4*)(Ep + 1048576 + e);
  f32x4 a2 = *(const f32x4*)(Ep + 2097152 + e);
  f32x4 a3 = *(const f32x4*)(Ep + 3145728 + e);
  f32x4 bb = *(const f32x4*)(bemb + (e & 1023));
  short4v hv, lv;
#pragma unroll
  for (int j = 0; j < 4; ++j) {
    float x = a0[j] + a1[j] + a2[j] + a3[j] + bb[j];
    x = fmaxf(x, 0.0f);
    bf16 h = __float2bfloat16(x);
    hv[j] = __builtin_bit_cast(short, h);
    lv[j] = bfbits(x - __bfloat162float(h));
  }
  *(short4v*)((short*)vhi + e) = hv;
  *(short4v*)((short*)vlo + e) = lv;
}

// ---------------------------------------------------------------------------
// xgates (dbuf): Gx[rt] = vh@W1ih_h + vl@W1ih_h + vh@W1ih_l.
// A = v ring bf16 (pre-split); B = W1ih fp32, cvt at LDS-write. 16 chunks.
// Block map: x=bid&7 (XCD), s=bid>>3; ct = x*4+(s&3), rt = s>>2.
// ---------------------------------------------------------------------------
__global__ __launch_bounds__(256, 1) void k_xgates(
    const bf16* __restrict__ vhi, const bf16* __restrict__ vlo,
    const float* __restrict__ Wih1, float* __restrict__ Gx)
{
  __shared__ __align__(16) short ls[65536];
  const int x  = blockIdx.x & 7;
  const int s  = blockIdx.x >> 3;
  const int ct = x * 4 + (s & 3);
  const int rt = s >> 2;

  STAGE_IDX
  FRAG_IDX
  const bf16* arh[4];
  const bf16* arl[4];
  const float* brow[4];
#pragma unroll
  for (int i = 0; i < 4; ++i) {
    arh[i] = vhi + (size_t)rt * 131072 + (size_t)srow[i] * 1024 + sseg[i] * 8;
    arl[i] = vlo + (size_t)rt * 131072 + (size_t)srow[i] * 1024 + sseg[i] * 8;
    brow[i] = Wih1 + (size_t)(ct * 128 + srow[i]) * 1024 + sseg[i] * 8;
  }

  short8 rah[4], ral[4];
  f32x4 fb[4][2];
  auto LOAD = [&](int c) {
#pragma unroll
    for (int i = 0; i < 4; ++i) {
      rah[i] = *(const short8*)(arh[i] + c * 64);
      ral[i] = *(const short8*)(arl[i] + c * 64);
      fb[i][0] = *(const f32x4*)(brow[i] + c * 64);
      fb[i][1] = *(const f32x4*)(brow[i] + c * 64 + 4);
    }
  };
  auto STORE = [&](int buf) {
    short* p = ls + buf * BUF;
#pragma unroll
    for (int i = 0; i < 4; ++i) {
      int o = srow[i] * 64 + ssw[i];
      *(short8*)(p + o)        = rah[i];
      *(short8*)(p + TILE + o) = ral[i];
      short8 hi, lo;
      cvtfp(fb[i][0], fb[i][1], hi, lo);
      *(short8*)(p + 2 * TILE + o) = hi;
      *(short8*)(p + 3 * TILE + o) = lo;
    }
  };

  f32x4 acc[4][4] = {};
  LOAD(0); STORE(0);
  LOAD(1);
  __syncthreads();

  for (int c = 0; c < 16; ++c) {
    if (c + 1 < 16) STORE((c + 1) & 1);
    if (c + 2 < 16) LOAD(c + 2);
    const short* la = ls + (c & 1) * BUF;
#pragma unroll
    for (int ks = 0; ks < 2; ++ks) {
      short8 afh[4], afl[4], bfh[4], bfl[4];
      int asw[4], bsw[4];
#pragma unroll
      for (int f = 0; f < 4; ++f) {
        int ar = wr + f * 16 + m;
        asw[f] = ar * 64 + (((ks * 4 + kg) ^ (ar & 7)) * 8);
        int br = wc + f * 16 + m;
        bsw[f] = br * 64 + (((ks * 4 + kg) ^ (br & 7)) * 8);
        afh[f] = *(const short8*)(la + asw[f]);
        bfh[f] = *(const short8*)(la + 2 * TILE + bsw[f]);
      }
#pragma unroll
      for (int fr = 0; fr < 4; ++fr)
#pragma unroll
        for (int fc = 0; fc < 4; ++fc)
          acc[fr][fc] = __builtin_amdgcn_mfma_f32_16x16x32_bf16(afh[fr], bfh[fc], acc[fr][fc], 0, 0, 0);
#pragma unroll
      for (int f = 0; f < 4; ++f)
        afl[f] = *(const short8*)(la + TILE + asw[f]);
#pragma unroll
      for (int fr = 0; fr < 4; ++fr)
#pragma unroll
        for (int fc = 0; fc < 4; ++fc)
          acc[fr][fc] = __builtin_amdgcn_mfma_f32_16x16x32_bf16(afl[fr], bfh[fc], acc[fr][fc], 0, 0, 0);
#pragma unroll
      for (int f = 0; f < 4; ++f)
        bfl[f] = *(const short8*)(la + 3 * TILE + bsw[f]);
#pragma unroll
      for (int fr = 0; fr < 4; ++fr)
#pragma unroll
        for (int fc = 0; fc < 4; ++fc)
          acc[fr][fc] = __builtin_amdgcn_mfma_f32_16x16x32_bf16(afh[fr], bfl[fc], acc[fr][fc], 0, 0, 0);
    }
    if (c + 1 < 16) __syncthreads();
  }

  epilogue(acc, [&](int lrow, int lcol, float aval) {
    Gx[(size_t)rt * 524288 + (size_t)lrow * 4096 + ct * 128 + lcol] = aval;
  });
}

// ---------------------------------------------------------------------------
// G_k (h-side): grid 128, job = bid>>5, ct = bid&31.
//  job0/1: h1n(1-s) @ w1hh 3-product split, K-halves -> P0/P1
//  job2:   h1n*s @ w2ih_h 2-product -> P2    job3: h2 @ w2hh_h 2-prod -> P3
// Single gemm3 + single gemm2 call site (compile-time hardening).
// ---------------------------------------------------------------------------
__global__ __launch_bounds__(256, 1) void k_step(
    const bf16* __restrict__ h1nh, const bf16* __restrict__ h1nl,
    const bf16* __restrict__ h2h, const bf16* __restrict__ h2l,
    const bf16* __restrict__ w1hh_h, const bf16* __restrict__ w1hh_l,
    const bf16* __restrict__ w2ih_h, const bf16* __restrict__ w2hh_h,
    const float* __restrict__ sm, float* __restrict__ R, int k)
{
  __shared__ __align__(16) short ls[65536];
  const int job = blockIdx.x >> 5;
  const int ct  = blockIdx.x & 31;
  if (k == 64 && job < 2) return;   // E_64 only consumes lstm2 partials

  f32x4 acc[4][4] = {};
  const size_t cto = (size_t)ct * 131072;
  if (job < 2) {
    const size_t ko = (size_t)job * 512;
    gemm3(h1nh + ko, h1nl + ko, w1hh_h + cto + ko, w1hh_l + cto + ko,
          8, sm, 0, ls, acc);
  } else {
    const bf16* A0 = (job == 2) ? h1nh : h2h;
    const bf16* A1 = (job == 2) ? h1nl : h2l;
    const bf16* B  = (job == 2) ? (w2ih_h + cto) : (w2hh_h + cto);
    const float* smp = (job == 2) ? sm : nullptr;
    gemm2(A0, A1, B, 16, smp, 1, ls, acc);
  }

  float* Rout = R + (size_t)job * 524288;
  epilogue(acc, [&](int lrow, int lcol, float aval) {
    Rout[(size_t)lrow * 4096 + ct * 128 + lcol] = aval;
  });
}

// ---------------------------------------------------------------------------
// E_k: grid 128 (b = blockIdx), 512 threads, 2 j each.
// Inline zx (fp64 v.u); lstm1 gates = Gx[k&7] + P0 + P1 (k>0) + b1;
// lstm2 gates = P2 + P3. Writes unmasked h1n hi/lo + s mask.
// ---------------------------------------------------------------------------
__global__ void k_elem(const float* __restrict__ R, const float* __restrict__ Gx,
                       const bf16* __restrict__ vhi, const bf16* __restrict__ vlo,
                       const double* __restrict__ uvec, const double* __restrict__ cbdp,
                       float* __restrict__ craw,
                       bf16* __restrict__ h1nh, bf16* __restrict__ h1nl,
                       float* __restrict__ sm,
                       float* __restrict__ c2, bf16* __restrict__ h2h, bf16* __restrict__ h2l,
                       float* __restrict__ rdm, const double* __restrict__ wv,
                       const float* __restrict__ b1, float* __restrict__ dout, int k)
{
  __shared__ double red[8];
  const int tid = threadIdx.x;
  const int b   = blockIdx.x;
  const size_t broff = (size_t)b * 4096;
  const float* P0 = R + broff;
  const float* P1 = P0 + 524288;
  const float* P2 = P0 + 2 * 524288;
  const float* P3 = P0 + 3 * 524288;
  const float* GX = Gx + (size_t)(k & 7) * 524288 + broff;

  if (k < 64) {  // boundary gate + lstm1 step k
    const bf16* vhr = vhi + (size_t)(k & 7) * 131072 + (size_t)b * 1024;
    const bf16* vlr = vlo + (size_t)(k & 7) * 131072 + (size_t)b * 1024;
    double za = 0.0;
#pragma unroll
    for (int ji = 0; ji < 2; ++ji) {
      int j = tid + ji * 512;
      za += (double)(__bfloat162float(vhr[j]) + __bfloat162float(vlr[j])) * uvec[j];
    }
#pragma unroll
    for (int o = 32; o > 0; o >>= 1) za += __shfl_down(za, o, 64);
    if ((tid & 63) == 0) red[tid >> 6] = za;
    __syncthreads();
    float zpre = (float)(red[0] + red[1] + red[2] + red[3] +
                         red[4] + red[5] + red[6] + red[7] + cbdp[0]);
    if (k > 0) zpre += rdm[(k - 1) * 128 + b];
    float s  = (sigm(zpre) > 0.5f) ? 1.0f : 0.0f;   // round(): 0.5 -> 0
    float om = 1.0f - s;
    __syncthreads();   // red about to be reused

    double rd = 0.0;
#pragma unroll
    for (int ji = 0; ji < 2; ++ji) {
      int j = tid + ji * 512;
      float gi = GX[j]        + b1[j];
      float gf = GX[1024 + j] + b1[1024 + j];
      float gg = GX[2048 + j] + b1[2048 + j];
      float go = GX[3072 + j] + b1[3072 + j];
      if (k > 0) {
        gi += P0[j]        + P1[j];
        gf += P0[1024 + j] + P1[1024 + j];
        gg += P0[2048 + j] + P1[2048 + j];
        go += P0[3072 + j] + P1[3072 + j];
      }
      float cn = sigm(gf) * craw[b * 1024 + j] + sigm(gi) * tanhf(gg);
      float hn = sigm(go) * tanhf(cn);
      craw[b * 1024 + j] = om * cn;
      bf16 hh = __float2bfloat16(hn);
      h1nh[b * 1024 + j] = hh;
      h1nl[b * 1024 + j] = __float2bfloat16(hn - __bfloat162float(hh));
      rd += (double)hn * wv[j];
    }
#pragma unroll
    for (int o = 32; o > 0; o >>= 1) rd += __shfl_down(rd, o, 64);
    if ((tid & 63) == 0) red[tid >> 6] = rd;
    __syncthreads();
    if (tid == 0) {
      rdm[k * 128 + b] = om * (float)(red[0] + red[1] + red[2] + red[3] +
                                      red[4] + red[5] + red[6] + red[7]);
      sm[b] = s;
    }
  }

  if (k >= 1) {  // lstm2 step k-1 (x pre-masked by s_{k-1} in k_step; bias-free)
#pragma unroll
    for (int ji = 0; ji < 2; ++ji) {
      int j = tid + ji * 512;
      float gi = P2[j]        + P3[j];
      float gf = P2[1024 + j] + P3[1024 + j];
      float gg = P2[2048 + j] + P3[2048 + j];
      float go = P2[3072 + j] + P3[3072 + j];
      float cn = sigm(gf) * c2[b * 1024 + j] + sigm(gi) * tanhf(gg);
      float hn = sigm(go) * tanhf(cn);
      c2[b * 1024 + j] = cn;
      bf16 hh = __float2bfloat16(hn);
      h2h[b * 1024 + j] = hh;
      h2l[b * 1024 + j] = __float2bfloat16(hn - __bfloat162float(hh));
      if (k == 64) dout[b * 1024 + j] = hn;
    }
  }
}

// ---------------------------------------------------------------------------
extern "C" void kernel_launch(void* const* d_in, const int* in_sizes, int n_in,
                              void* d_out, int out_size, void* d_ws, size_t ws_size,
                              hipStream_t stream) {
  const float* video = (const float*)d_in[0];
  const float* Wemb  = (const float*)d_in[1];
  const float* bemb  = (const float*)d_in[2];
  const float* Wih1  = (const float*)d_in[3];
  const float* Whh1  = (const float*)d_in[4];
  const float* b1    = (const float*)d_in[5];
  const float* Wsi   = (const float*)d_in[6];
  const float* Wsh   = (const float*)d_in[7];
  const float* bbd   = (const float*)d_in[8];
  const float* vs    = (const float*)d_in[9];
  const float* Wih2  = (const float*)d_in[10];
  const float* Whh2  = (const float*)d_in[11];
  float* dout = (float*)d_out;

  static const int exp_sizes[12] = {
    128 * 64 * 2048, 1024 * 2048, 1024, 4096 * 1024, 4096 * 1024, 4096,
    512 * 1024, 512 * 1024, 512, 512, 4096 * 1024, 4096 * 1024 };
  int bad = -1;
  if (n_in != 12) bad = 99;
  else if (out_size != 131072) bad = 98;
  else
    for (int i = 0; i < 12; ++i)
      if (in_sizes[i] != exp_sizes[i]) { bad = i; break; }
  if (bad >= 0) {
    k_diag<<<1, 64, 0, stream>>>(dout, 10000.0f + (float)bad);
    return;
  }

  char* ws = (char*)d_ws;
  size_t off = 0;
  auto alloc = [&](size_t bytes) {
    char* p = ws + off;
    off += (bytes + 255) & ~(size_t)255;
    return p;
  };
  // zero region (state), memset each launch
  bf16*  h1nh = (bf16*)alloc(262144);
  bf16*  h1nl = (bf16*)alloc(262144);
  bf16*  h2h  = (bf16*)alloc(262144);
  bf16*  h2l  = (bf16*)alloc(262144);
  float* c2   = (float*)alloc(524288);
  float* craw = (float*)alloc(524288);
  float* sm   = (float*)alloc(512);
  const size_t zeroBytes = off;
  // rest (written before read every launch)
  double* u    = (double*)alloc(8192);
  double* wvv  = (double*)alloc(8192);
  double* cbdp = (double*)alloc(256);
  float* rdm   = (float*)alloc(64 * 128 * 4);
  bf16* w1hh_h = (bf16*)alloc(8388608);
  bf16* w1hh_l = (bf16*)alloc(8388608);
  bf16* w2ih_h = (bf16*)alloc(8388608);
  bf16* w2hh_h = (bf16*)alloc(8388608);
  float* R     = (float*)alloc(4 * 2097152);            // 4 partials, 8.4 MB
  float* Gxf   = (float*)alloc(8 * 2097152);            // Gx ring / embed Ep alias
  bf16* vhi    = (bf16*)alloc(8 * 131072 * 2);          // v ring, 8 slots
  bf16* vlo    = (bf16*)alloc(8 * 131072 * 2);

  if (ws_size < off) {
    k_diag<<<1, 64, 0, stream>>>(dout, 100.0f + (float)(ws_size >> 20));
    return;
  }

  (void)hipMemsetAsync(d_ws, 0, zeroBytes, stream);
  k_uw<<<9, 256, 0, stream>>>(Wsi, Wsh, bbd, vs, u, wvv, cbdp);
  k_wsplit<<<12288, 256, 0, stream>>>(Whh1, Wih2, Whh2,
                                      w1hh_h, w1hh_l, w2ih_h, w2hh_h);

  for (int k = 0; k <= 64; ++k) {
    if (k < 64 && (k & 7) == 0) {
      k_embed<<<256, 256, 0, stream>>>(video, Wemb, Gxf, k);          // Ep alias
      k_efin<<<1024, 256, 0, stream>>>(Gxf, bemb, vhi, vlo);
      k_xgates<<<256, 256, 0, stream>>>(vhi, vlo, Wih1, Gxf);         // writes Gx
    }
    if (k > 0)
      k_step<<<128, 256, 0, stream>>>(h1nh, h1nl, h2h, h2l,
                                      w1hh_h, w1hh_l, w2ih_h, w2hh_h, sm, R, k);
    k_elem<<<128, 512, 0, stream>>>(R, Gxf, vhi, vlo, u, cbdp, craw,
                                    h1nh, h1nl, sm, c2, h2h, h2l,
                                    rdm, wvv, b1, dout, k);
  }
}

// Round 5
// 2632.091 us; speedup vs baseline: 1.2905x; 1.0224x over previous
//
#include <hip/hip_runtime.h>
#include <hip/hip_bf16.h>
#include <math.h>

// EncoderRNN on MI355X. Inputs fp32, output fp32.
// R16 = R15 + full-machine k_step: 8 jobs x 32 ct = 256 blocks, all K-sliced
// (w1hh 3-prod K-quarters -> P0/P1; w2ih / w2hh 2-prod K-halves -> P2/P3).
// Each partial gets exactly 2 atomicAdd contributions (commutative -> exact
// determinism); R memset once at start; k_elem zeroes each P element after
// consuming it (restores the atomic-accumulator invariant per step).
// Everything else identical to R15 (passed, 2691 us):
// fused-product staging GEMMs, 128 KB dbuf LDS, depth-2 load issue, fp32
// sources cvt-at-LDS-write; embed path per 8 steps (k_embed K-split x4 ->
// k_efin -> k_xgates); k_elem 512 thr with inline fp64 zx dot.

typedef __attribute__((ext_vector_type(8))) short short8;
typedef __attribute__((ext_vector_type(4))) short short4v;
typedef __attribute__((ext_vector_type(4))) float f32x4;
typedef __hip_bfloat16 bf16;

__device__ __forceinline__ float sigm(float x) { return 1.0f / (1.0f + expf(-x)); }
__device__ __forceinline__ short bfbits(float x) {
  bf16 h = __float2bfloat16(x);
  return __builtin_bit_cast(short, h);
}
// two f32x4 (regs) -> bf16 hi + residual lo
__device__ __forceinline__ void cvtfp(const f32x4 a, const f32x4 b,
                                      short8& hi, short8& lo)
{
#pragma unroll
  for (int j = 0; j < 8; ++j) {
    float x = (j < 4) ? a[j] : b[j - 4];
    bf16 h = __float2bfloat16(x);
    hi[j] = __builtin_bit_cast(short, h);
    lo[j] = bfbits(x - __bfloat162float(h));
  }
}

// LDS geometry: tile = 128x64 bf16 = 8192 shorts. Buffer = 4 tiles = 32768
// shorts (64 KB). Double buffer = 65536 shorts (128 KB). XOR-swizzled.
#define TILE 8192
#define BUF  32768

// staging indices (row/seg/swizzled-offset) for 256 threads x 4 iters
#define STAGE_IDX                                              \
  int srow[4], sseg[4], ssw[4];                                \
  _Pragma("unroll")                                            \
  for (int i = 0; i < 4; ++i) {                                \
    int linear = i * 256 + threadIdx.x;                        \
    srow[i] = linear >> 3;                                     \
    sseg[i] = linear & 7;                                      \
    ssw[i]  = (sseg[i] ^ (srow[i] & 7)) * 8;                   \
  }

// MFMA fragment constants
#define FRAG_IDX                                               \
  const int lane = threadIdx.x & 63, wave = threadIdx.x >> 6;  \
  const int wr = (wave & 1) * 64, wc = (wave >> 1) * 64;       \
  const int m = lane & 15, kg = lane >> 4;

// ---------------------------------------------------------------------------
// gemm3: acc += Ah@Bh^T + Al@Bh^T + Ah@Bl^T over nChunks K-chunks of 64.
// A row-major [128][1024] (pre-offset), B row-major [128][1024] (pre-offset).
// Optional A-row mask: keep iff (smk[row]>0.5)==(pol!=0).
// ---------------------------------------------------------------------------
__device__ __forceinline__ void gemm3(
    const bf16* __restrict__ Ah, const bf16* __restrict__ Al,
    const bf16* __restrict__ Bh, const bf16* __restrict__ Bl,
    int nChunks, const float* __restrict__ smk, int pol,
    short* ls, f32x4 acc[4][4])
{
  STAGE_IDX
  FRAG_IDX
  bool keep[4];
#pragma unroll
  for (int i = 0; i < 4; ++i)
    keep[i] = (smk == nullptr) || ((smk[srow[i]] > 0.5f) == (pol != 0));

  const short8 zz = {};
  short8 rah[4], ral[4], rbh[4], rbl[4];

  auto LOAD = [&](int c) {
#pragma unroll
    for (int i = 0; i < 4; ++i) {
      size_t o = (size_t)srow[i] * 1024 + c * 64 + sseg[i] * 8;
      rah[i] = keep[i] ? *(const short8*)(Ah + o) : zz;
      ral[i] = keep[i] ? *(const short8*)(Al + o) : zz;
      rbh[i] = *(const short8*)(Bh + o);
      rbl[i] = *(const short8*)(Bl + o);
    }
  };
  auto STORE = [&](int buf) {
    short* p = ls + buf * BUF;
#pragma unroll
    for (int i = 0; i < 4; ++i) {
      int o = srow[i] * 64 + ssw[i];
      *(short8*)(p + o)            = rah[i];
      *(short8*)(p + TILE + o)     = ral[i];
      *(short8*)(p + 2 * TILE + o) = rbh[i];
      *(short8*)(p + 3 * TILE + o) = rbl[i];
    }
  };

  LOAD(0); STORE(0);
  if (nChunks > 1) LOAD(1);
  __syncthreads();

  for (int c = 0; c < nChunks; ++c) {
    if (c + 1 < nChunks) STORE((c + 1) & 1);
    if (c + 2 < nChunks) LOAD(c + 2);
    const short* la = ls + (c & 1) * BUF;
#pragma unroll
    for (int ks = 0; ks < 2; ++ks) {
      short8 afh[4], afl[4], bfh[4], bfl[4];
      int asw[4], bsw[4];
#pragma unroll
      for (int f = 0; f < 4; ++f) {
        int ar = wr + f * 16 + m;
        asw[f] = ar * 64 + (((ks * 4 + kg) ^ (ar & 7)) * 8);
        int br = wc + f * 16 + m;
        bsw[f] = br * 64 + (((ks * 4 + kg) ^ (br & 7)) * 8);
        afh[f] = *(const short8*)(la + asw[f]);
        bfh[f] = *(const short8*)(la + 2 * TILE + bsw[f]);
      }
#pragma unroll
      for (int fr = 0; fr < 4; ++fr)
#pragma unroll
        for (int fc = 0; fc < 4; ++fc)
          acc[fr][fc] = __builtin_amdgcn_mfma_f32_16x16x32_bf16(afh[fr], bfh[fc], acc[fr][fc], 0, 0, 0);
#pragma unroll
      for (int f = 0; f < 4; ++f)
        afl[f] = *(const short8*)(la + TILE + asw[f]);
#pragma unroll
      for (int fr = 0; fr < 4; ++fr)
#pragma unroll
        for (int fc = 0; fc < 4; ++fc)
          acc[fr][fc] = __builtin_amdgcn_mfma_f32_16x16x32_bf16(afl[fr], bfh[fc], acc[fr][fc], 0, 0, 0);
#pragma unroll
      for (int f = 0; f < 4; ++f)
        bfl[f] = *(const short8*)(la + 3 * TILE + bsw[f]);
#pragma unroll
      for (int fr = 0; fr < 4; ++fr)
#pragma unroll
        for (int fc = 0; fc < 4; ++fc)
          acc[fr][fc] = __builtin_amdgcn_mfma_f32_16x16x32_bf16(afh[fr], bfl[fc], acc[fr][fc], 0, 0, 0);
    }
    if (c + 1 < nChunks) __syncthreads();
  }
}

// ---------------------------------------------------------------------------
// gemm2: acc += Ah@B^T + Al@B^T (B hi-only).
// ---------------------------------------------------------------------------
__device__ __forceinline__ void gemm2(
    const bf16* __restrict__ Ah, const bf16* __restrict__ Al,
    const bf16* __restrict__ B,
    int nChunks, const float* __restrict__ smk, int pol,
    short* ls, f32x4 acc[4][4])
{
  STAGE_IDX
  FRAG_IDX
  bool keep[4];
#pragma unroll
  for (int i = 0; i < 4; ++i)
    keep[i] = (smk == nullptr) || ((smk[srow[i]] > 0.5f) == (pol != 0));

  const short8 zz = {};
  short8 rah[4], ral[4], rb[4];

  auto LOAD = [&](int c) {
#pragma unroll
    for (int i = 0; i < 4; ++i) {
      size_t o = (size_t)srow[i] * 1024 + c * 64 + sseg[i] * 8;
      rah[i] = keep[i] ? *(const short8*)(Ah + o) : zz;
      ral[i] = keep[i] ? *(const short8*)(Al + o) : zz;
      rb[i]  = *(const short8*)(B + o);
    }
  };
  auto STORE = [&](int buf) {
    short* p = ls + buf * BUF;
#pragma unroll
    for (int i = 0; i < 4; ++i) {
      int o = srow[i] * 64 + ssw[i];
      *(short8*)(p + o)            = rah[i];
      *(short8*)(p + TILE + o)     = ral[i];
      *(short8*)(p + 2 * TILE + o) = rb[i];
    }
  };

  LOAD(0); STORE(0);
  if (nChunks > 1) LOAD(1);
  __syncthreads();

  for (int c = 0; c < nChunks; ++c) {
    if (c + 1 < nChunks) STORE((c + 1) & 1);
    if (c + 2 < nChunks) LOAD(c + 2);
    const short* la = ls + (c & 1) * BUF;
#pragma unroll
    for (int ks = 0; ks < 2; ++ks) {
      short8 afh[4], afl[4], bf[4];
      int asw[4], bsw[4];
#pragma unroll
      for (int f = 0; f < 4; ++f) {
        int ar = wr + f * 16 + m;
        asw[f] = ar * 64 + (((ks * 4 + kg) ^ (ar & 7)) * 8);
        int br = wc + f * 16 + m;
        bsw[f] = br * 64 + (((ks * 4 + kg) ^ (br & 7)) * 8);
        afh[f] = *(const short8*)(la + asw[f]);
        bf[f]  = *(const short8*)(la + 2 * TILE + bsw[f]);
      }
#pragma unroll
      for (int fr = 0; fr < 4; ++fr)
#pragma unroll
        for (int fc = 0; fc < 4; ++fc)
          acc[fr][fc] = __builtin_amdgcn_mfma_f32_16x16x32_bf16(afh[fr], bf[fc], acc[fr][fc], 0, 0, 0);
#pragma unroll
      for (int f = 0; f < 4; ++f)
        afl[f] = *(const short8*)(la + TILE + asw[f]);
#pragma unroll
      for (int fr = 0; fr < 4; ++fr)
#pragma unroll
        for (int fc = 0; fc < 4; ++fc)
          acc[fr][fc] = __builtin_amdgcn_mfma_f32_16x16x32_bf16(afl[fr], bf[fc], acc[fr][fc], 0, 0, 0);
    }
    if (c + 1 < nChunks) __syncthreads();
  }
}

// C/D frag layout (m89/m91-verified): col = lane&15, row = (lane>>4)*4 + reg.
template <typename F>
__device__ __forceinline__ void epilogue(const f32x4 acc[4][4], F&& body)
{
  FRAG_IDX
#pragma unroll
  for (int fr = 0; fr < 4; ++fr)
#pragma unroll
    for (int fc = 0; fc < 4; ++fc)
#pragma unroll
      for (int r = 0; r < 4; ++r)
        body(wr + fr * 16 + kg * 4 + r, wc + fc * 16 + m, acc[fr][fc][r]);
}

// ---------------------------------------------------------------------------
__global__ void k_diag(float* __restrict__ out, float val)
{
  if (threadIdx.x == 0 && blockIdx.x == 0) out[0] = val;
}

// u[h]=sum_m vs[m]*Wsi[m,h]; w[h]=sum_m vs[m]*Wsh[m,h]; cbd=b_bd.vs (fp64)
__global__ void k_uw(const float* __restrict__ Wsi, const float* __restrict__ Wsh,
                     const float* __restrict__ bbd, const float* __restrict__ vs,
                     double* __restrict__ u, double* __restrict__ wv,
                     double* __restrict__ cbdp)
{
  const int blk = blockIdx.x;
  if (blk < 8) {
    const float* W = (blk < 4) ? Wsi : Wsh;
    double* out = (blk < 4) ? u : wv;
    int h = (blk & 3) * 256 + threadIdx.x;
    double a = 0.0;
    for (int mm = 0; mm < 512; ++mm)
      a += (double)vs[mm] * (double)W[mm * 1024 + h];
    out[h] = a;
  } else if (threadIdx.x < 64) {
    double a = 0.0;
    for (int mm = threadIdx.x; mm < 512; mm += 64)
      a += (double)vs[mm] * (double)bbd[mm];
#pragma unroll
    for (int o = 32; o > 0; o >>= 1) a += __shfl_down(a, o, 64);
    if (threadIdx.x == 0) cbdp[0] = a;
  }
}

// weight split: m0 = w1hh -> hi+lo; m1 = w2ih -> hi; m2 = w2hh -> hi
__global__ void k_wsplit(const float* __restrict__ w1hh, const float* __restrict__ w2ih,
                         const float* __restrict__ w2hh,
                         bf16* __restrict__ o1hh_h, bf16* __restrict__ o1hh_l,
                         bf16* __restrict__ o2ih_h, bf16* __restrict__ o2hh_h)
{
  const int m = blockIdx.x >> 12;
  const size_t i4 = (size_t)(blockIdx.x & 4095) * 256 + threadIdx.x;
  const float* src = (m == 0) ? w1hh : (m == 1) ? w2ih : w2hh;
  bf16* dh = (m == 0) ? o1hh_h : (m == 1) ? o2ih_h : o2hh_h;
  bf16* dl = (m == 0) ? o1hh_l : nullptr;
  f32x4 v = *(const f32x4*)(src + i4 * 4);
  short4v hv, lv;
#pragma unroll
  for (int j = 0; j < 4; ++j) {
    float x = v[j];
    bf16 h = __float2bfloat16(x);
    hv[j] = __builtin_bit_cast(short, h);
    lv[j] = bfbits(x - __bfloat162float(h));
  }
  *(short4v*)((short*)dh + i4 * 4) = hv;
  if (dl) *(short4v*)((short*)dl + i4 * 4) = lv;
}

// ---------------------------------------------------------------------------
// embed (K-split x4, dbuf): Ep[kh] += video(Krange) @ Wemb(Krange)^T with the
// fused 3-product split. fp32 loads staged raw in regs; cvt at LDS-write.
// Block = (tl 0..7, ct 0..7, kh 0..3); 8 chunks.
// ---------------------------------------------------------------------------
__global__ __launch_bounds__(256, 1) void k_embed(
    const float* __restrict__ video, const float* __restrict__ Wemb,
    float* __restrict__ Ep, int tbase)
{
  __shared__ __align__(16) short ls[65536];
  const int tl = blockIdx.x >> 5;
  const int ct = (blockIdx.x >> 2) & 7;
  const int kh = blockIdx.x & 3;

  STAGE_IDX
  FRAG_IDX
  const float* arow[4];
  const float* brow[4];
#pragma unroll
  for (int i = 0; i < 4; ++i) {
    arow[i] = video + (size_t)(srow[i] * 64 + tbase + tl) * 2048 + kh * 512 + sseg[i] * 8;
    brow[i] = Wemb + (size_t)(ct * 128 + srow[i]) * 2048 + kh * 512 + sseg[i] * 8;
  }

  f32x4 fa[4][2], fb[4][2];
  auto LOAD = [&](int c) {
#pragma unroll
    for (int i = 0; i < 4; ++i) {
      fa[i][0] = *(const f32x4*)(arow[i] + c * 64);
      fa[i][1] = *(const f32x4*)(arow[i] + c * 64 + 4);
      fb[i][0] = *(const f32x4*)(brow[i] + c * 64);
      fb[i][1] = *(const f32x4*)(brow[i] + c * 64 + 4);
    }
  };
  auto STORE = [&](int buf) {
    short* p = ls + buf * BUF;
#pragma unroll
    for (int i = 0; i < 4; ++i) {
      short8 hi, lo;
      int o = srow[i] * 64 + ssw[i];
      cvtfp(fa[i][0], fa[i][1], hi, lo);
      *(short8*)(p + o)        = hi;
      *(short8*)(p + TILE + o) = lo;
      cvtfp(fb[i][0], fb[i][1], hi, lo);
      *(short8*)(p + 2 * TILE + o) = hi;
      *(short8*)(p + 3 * TILE + o) = lo;
    }
  };

  f32x4 acc[4][4] = {};
  LOAD(0); STORE(0);
  LOAD(1);
  __syncthreads();

  for (int c = 0; c < 8; ++c) {
    if (c + 1 < 8) STORE((c + 1) & 1);
    if (c + 2 < 8) LOAD(c + 2);
    const short* la = ls + (c & 1) * BUF;
#pragma unroll
    for (int ks = 0; ks < 2; ++ks) {
      short8 afh[4], afl[4], bfh[4], bfl[4];
      int asw[4], bsw[4];
#pragma unroll
      for (int f = 0; f < 4; ++f) {
        int ar = wr + f * 16 + m;
        asw[f] = ar * 64 + (((ks * 4 + kg) ^ (ar & 7)) * 8);
        int br = wc + f * 16 + m;
        bsw[f] = br * 64 + (((ks * 4 + kg) ^ (br & 7)) * 8);
        afh[f] = *(const short8*)(la + asw[f]);
        bfh[f] = *(const short8*)(la + 2 * TILE + bsw[f]);
      }
#pragma unroll
      for (int fr = 0; fr < 4; ++fr)
#pragma unroll
        for (int fc = 0; fc < 4; ++fc)
          acc[fr][fc] = __builtin_amdgcn_mfma_f32_16x16x32_bf16(afh[fr], bfh[fc], acc[fr][fc], 0, 0, 0);
#pragma unroll
      for (int f = 0; f < 4; ++f)
        afl[f] = *(const short8*)(la + TILE + asw[f]);
#pragma unroll
      for (int fr = 0; fr < 4; ++fr)
#pragma unroll
        for (int fc = 0; fc < 4; ++fc)
          acc[fr][fc] = __builtin_amdgcn_mfma_f32_16x16x32_bf16(afl[fr], bfh[fc], acc[fr][fc], 0, 0, 0);
#pragma unroll
      for (int f = 0; f < 4; ++f)
        bfl[f] = *(const short8*)(la + 3 * TILE + bsw[f]);
#pragma unroll
      for (int fr = 0; fr < 4; ++fr)
#pragma unroll
        for (int fc = 0; fc < 4; ++fc)
          acc[fr][fc] = __builtin_amdgcn_mfma_f32_16x16x32_bf16(afh[fr], bfl[fc], acc[fr][fc], 0, 0, 0);
    }
    if (c + 1 < 8) __syncthreads();
  }

  epilogue(acc, [&](int lrow, int lcol, float aval) {
    Ep[(size_t)kh * 1048576 + (size_t)(tl * 128 + lrow) * 1024 + ct * 128 + lcol] = aval;
  });
}

// sum 4 K-partials + bias, relu, split -> v ring (slot-linear)
__global__ void k_efin(const float* __restrict__ Ep, const float* __restrict__ bemb,
                       bf16* __restrict__ vhi, bf16* __restrict__ vlo)
{
  const size_t e = ((size_t)blockIdx.x * 256 + threadIdx.x) * 4;
  f32x4 a0 = *(const f32x4*)(Ep + e);
  f32x4 a1 = *(const f32x4*)(Ep + 1048576 + e);
  f32x4 a2 = *(const f32x4*)(Ep + 2097152 + e);
  f32x4 a3 = *(const f32x4*)(Ep + 3145728 + e);
  f32x4 bb = *(const f32x4*)(bemb + (e & 1023));
  short4v hv, lv;
#pragma unroll
  for (int j = 0; j < 4; ++j) {
    float x = a0[j] + a1[j] + a2[j] + a3[j] + bb[j];
    x = fmaxf(x, 0.0f);
    bf16 h = __float2bfloat16(x);
    hv[j] = __builtin_bit_cast(short, h);
    lv[j] = bfbits(x - __bfloat162float(h));
  }
  *(short4v*)((short*)vhi + e) = hv;
  *(short4v*)((short*)vlo + e) = lv;
}

// ---------------------------------------------------------------------------
// xgates (dbuf): Gx[rt] = vh@W1ih_h + vl@W1ih_h + vh@W1ih_l.
// A = v ring bf16 (pre-split); B = W1ih fp32, cvt at LDS-write. 16 chunks.
// Block map: x=bid&7 (XCD), s=bid>>3; ct = x*4+(s&3), rt = s>>2.
// ---------------------------------------------------------------------------
__global__ __launch_bounds__(256, 1) void k_xgates(
    const bf16* __restrict__ vhi, const bf16* __restrict__ vlo,
    const float* __restrict__ Wih1, float* __restrict__ Gx)
{
  __shared__ __align__(16) short ls[65536];
  const int x  = blockIdx.x & 7;
  const int s  = blockIdx.x >> 3;
  const int ct = x * 4 + (s & 3);
  const int rt = s >> 2;

  STAGE_IDX
  FRAG_IDX
  const bf16* arh[4];
  const bf16* arl[4];
  const float* brow[4];
#pragma unroll
  for (int i = 0; i < 4; ++i) {
    arh[i] = vhi + (size_t)rt * 131072 + (size_t)srow[i] * 1024 + sseg[i] * 8;
    arl[i] = vlo + (size_t)rt * 131072 + (size_t)srow[i] * 1024 + sseg[i] * 8;
    brow[i] = Wih1 + (size_t)(ct * 128 + srow[i]) * 1024 + sseg[i] * 8;
  }

  short8 rah[4], ral[4];
  f32x4 fb[4][2];
  auto LOAD = [&](int c) {
#pragma unroll
    for (int i = 0; i < 4; ++i) {
      rah[i] = *(const short8*)(arh[i] + c * 64);
      ral[i] = *(const short8*)(arl[i] + c * 64);
      fb[i][0] = *(const f32x4*)(brow[i] + c * 64);
      fb[i][1] = *(const f32x4*)(brow[i] + c * 64 + 4);
    }
  };
  auto STORE = [&](int buf) {
    short* p = ls + buf * BUF;
#pragma unroll
    for (int i = 0; i < 4; ++i) {
      int o = srow[i] * 64 + ssw[i];
      *(short8*)(p + o)        = rah[i];
      *(short8*)(p + TILE + o) = ral[i];
      short8 hi, lo;
      cvtfp(fb[i][0], fb[i][1], hi, lo);
      *(short8*)(p + 2 * TILE + o) = hi;
      *(short8*)(p + 3 * TILE + o) = lo;
    }
  };

  f32x4 acc[4][4] = {};
  LOAD(0); STORE(0);
  LOAD(1);
  __syncthreads();

  for (int c = 0; c < 16; ++c) {
    if (c + 1 < 16) STORE((c + 1) & 1);
    if (c + 2 < 16) LOAD(c + 2);
    const short* la = ls + (c & 1) * BUF;
#pragma unroll
    for (int ks = 0; ks < 2; ++ks) {
      short8 afh[4], afl[4], bfh[4], bfl[4];
      int asw[4], bsw[4];
#pragma unroll
      for (int f = 0; f < 4; ++f) {
        int ar = wr + f * 16 + m;
        asw[f] = ar * 64 + (((ks * 4 + kg) ^ (ar & 7)) * 8);
        int br = wc + f * 16 + m;
        bsw[f] = br * 64 + (((ks * 4 + kg) ^ (br & 7)) * 8);
        afh[f] = *(const short8*)(la + asw[f]);
        bfh[f] = *(const short8*)(la + 2 * TILE + bsw[f]);
      }
#pragma unroll
      for (int fr = 0; fr < 4; ++fr)
#pragma unroll
        for (int fc = 0; fc < 4; ++fc)
          acc[fr][fc] = __builtin_amdgcn_mfma_f32_16x16x32_bf16(afh[fr], bfh[fc], acc[fr][fc], 0, 0, 0);
#pragma unroll
      for (int f = 0; f < 4; ++f)
        afl[f] = *(const short8*)(la + TILE + asw[f]);
#pragma unroll
      for (int fr = 0; fr < 4; ++fr)
#pragma unroll
        for (int fc = 0; fc < 4; ++fc)
          acc[fr][fc] = __builtin_amdgcn_mfma_f32_16x16x32_bf16(afl[fr], bfh[fc], acc[fr][fc], 0, 0, 0);
#pragma unroll
      for (int f = 0; f < 4; ++f)
        bfl[f] = *(const short8*)(la + 3 * TILE + bsw[f]);
#pragma unroll
      for (int fr = 0; fr < 4; ++fr)
#pragma unroll
        for (int fc = 0; fc < 4; ++fc)
          acc[fr][fc] = __builtin_amdgcn_mfma_f32_16x16x32_bf16(afh[fr], bfl[fc], acc[fr][fc], 0, 0, 0);
    }
    if (c + 1 < 16) __syncthreads();
  }

  epilogue(acc, [&](int lrow, int lcol, float aval) {
    Gx[(size_t)rt * 524288 + (size_t)lrow * 4096 + ct * 128 + lcol] = aval;
  });
}

// ---------------------------------------------------------------------------
// G_k (h-side): grid 256, job = bid>>5, ct = bid&31. All jobs K-sliced:
//  j0..j3: w1hh 3-prod K-quarters -> atomic P0 (j0,j1) / P1 (j2,j3)
//  j4,j5:  w2ih 2-prod K-halves  -> atomic P2
//  j6,j7:  w2hh 2-prod K-halves  -> atomic P3
// Each partial element gets exactly 2 contributions (commutative -> exact).
// Partials are zeroed by the consumer (k_elem) / initial memset.
// ---------------------------------------------------------------------------
__global__ __launch_bounds__(256, 1) void k_step(
    const bf16* __restrict__ h1nh, const bf16* __restrict__ h1nl,
    const bf16* __restrict__ h2h, const bf16* __restrict__ h2l,
    const bf16* __restrict__ w1hh_h, const bf16* __restrict__ w1hh_l,
    const bf16* __restrict__ w2ih_h, const bf16* __restrict__ w2hh_h,
    const float* __restrict__ sm, float* __restrict__ R, int k)
{
  __shared__ __align__(16) short ls[65536];
  const int job = blockIdx.x >> 5;
  const int ct  = blockIdx.x & 31;
  if (k == 64 && job < 4) return;   // E_64 only consumes lstm2 partials

  f32x4 acc[4][4] = {};
  const size_t cto = (size_t)ct * 131072;
  if (job < 4) {
    const size_t ko = (size_t)job * 256;
    gemm3(h1nh + ko, h1nl + ko, w1hh_h + cto + ko, w1hh_l + cto + ko,
          4, sm, 0, ls, acc);
  } else if (job < 6) {
    const size_t ko = (size_t)(job - 4) * 512;
    gemm2(h1nh + ko, h1nl + ko, w2ih_h + cto + ko, 8, sm, 1, ls, acc);
  } else {
    const size_t ko = (size_t)(job - 6) * 512;
    gemm2(h2h + ko, h2l + ko, w2hh_h + cto + ko, 8, nullptr, 0, ls, acc);
  }

  float* Rout = R + (size_t)(job >> 1) * 524288;
  epilogue(acc, [&](int lrow, int lcol, float aval) {
    atomicAdd(&Rout[(size_t)lrow * 4096 + ct * 128 + lcol], aval);
  });
}

// ---------------------------------------------------------------------------
// E_k: grid 128 (b = blockIdx), 512 threads, 2 j each.
// Inline zx (fp64 v.u); lstm1 gates = Gx[k&7] + P0 + P1 (k>0) + b1;
// lstm2 gates = P2 + P3. Consumed P elements are zeroed (atomic invariant).
// ---------------------------------------------------------------------------
__global__ void k_elem(float* __restrict__ R, const float* __restrict__ Gx,
                       const bf16* __restrict__ vhi, const bf16* __restrict__ vlo,
                       const double* __restrict__ uvec, const double* __restrict__ cbdp,
                       float* __restrict__ craw,
                       bf16* __restrict__ h1nh, bf16* __restrict__ h1nl,
                       float* __restrict__ sm,
                       float* __restrict__ c2, bf16* __restrict__ h2h, bf16* __restrict__ h2l,
                       float* __restrict__ rdm, const double* __restrict__ wv,
                       const float* __restrict__ b1, float* __restrict__ dout, int k)
{
  __shared__ double red[8];
  const int tid = threadIdx.x;
  const int b   = blockIdx.x;
  const size_t broff = (size_t)b * 4096;
  float* P0 = R + broff;
  float* P1 = P0 + 524288;
  float* P2 = P0 + 2 * 524288;
  float* P3 = P0 + 3 * 524288;
  const float* GX = Gx + (size_t)(k & 7) * 524288 + broff;

  if (k < 64) {  // boundary gate + lstm1 step k
    const bf16* vhr = vhi + (size_t)(k & 7) * 131072 + (size_t)b * 1024;
    const bf16* vlr = vlo + (size_t)(k & 7) * 131072 + (size_t)b * 1024;
    double za = 0.0;
#pragma unroll
    for (int ji = 0; ji < 2; ++ji) {
      int j = tid + ji * 512;
      za += (double)(__bfloat162float(vhr[j]) + __bfloat162float(vlr[j])) * uvec[j];
    }
#pragma unroll
    for (int o = 32; o > 0; o >>= 1) za += __shfl_down(za, o, 64);
    if ((tid & 63) == 0) red[tid >> 6] = za;
    __syncthreads();
    float zpre = (float)(red[0] + red[1] + red[2] + red[3] +
                         red[4] + red[5] + red[6] + red[7] + cbdp[0]);
    if (k > 0) zpre += rdm[(k - 1) * 128 + b];
    float s  = (sigm(zpre) > 0.5f) ? 1.0f : 0.0f;   // round(): 0.5 -> 0
    float om = 1.0f - s;
    __syncthreads();   // red about to be reused

    double rd = 0.0;
#pragma unroll
    for (int ji = 0; ji < 2; ++ji) {
      int j = tid + ji * 512;
      float gi = GX[j]        + b1[j];
      float gf = GX[1024 + j] + b1[1024 + j];
      float gg = GX[2048 + j] + b1[2048 + j];
      float go = GX[3072 + j] + b1[3072 + j];
      if (k > 0) {
        gi += P0[j]        + P1[j];
        gf += P0[1024 + j] + P1[1024 + j];
        gg += P0[2048 + j] + P1[2048 + j];
        go += P0[3072 + j] + P1[3072 + j];
        // consume-and-clear for next step's atomic accumulation
        P0[j] = 0.0f; P0[1024 + j] = 0.0f; P0[2048 + j] = 0.0f; P0[3072 + j] = 0.0f;
        P1[j] = 0.0f; P1[1024 + j] = 0.0f; P1[2048 + j] = 0.0f; P1[3072 + j] = 0.0f;
      }
      float cn = sigm(gf) * craw[b * 1024 + j] + sigm(gi) * tanhf(gg);
      float hn = sigm(go) * tanhf(cn);
      craw[b * 1024 + j] = om * cn;
      bf16 hh = __float2bfloat16(hn);
      h1nh[b * 1024 + j] = hh;
      h1nl[b * 1024 + j] = __float2bfloat16(hn - __bfloat162float(hh));
      rd += (double)hn * wv[j];
    }
#pragma unroll
    for (int o = 32; o > 0; o >>= 1) rd += __shfl_down(rd, o, 64);
    if ((tid & 63) == 0) red[tid >> 6] = rd;
    __syncthreads();
    if (tid == 0) {
      rdm[k * 128 + b] = om * (float)(red[0] + red[1] + red[2] + red[3] +
                                      red[4] + red[5] + red[6] + red[7]);
      sm[b] = s;
    }
  }

  if (k >= 1) {  // lstm2 step k-1 (x pre-masked by s_{k-1} in k_step; bias-free)
#pragma unroll
    for (int ji = 0; ji < 2; ++ji) {
      int j = tid + ji * 512;
      float gi = P2[j]        + P3[j];
      float gf = P2[1024 + j] + P3[1024 + j];
      float gg = P2[2048 + j] + P3[2048 + j];
      float go = P2[3072 + j] + P3[3072 + j];
      // consume-and-clear for next step's atomic accumulation
      P2[j] = 0.0f; P2[1024 + j] = 0.0f; P2[2048 + j] = 0.0f; P2[3072 + j] = 0.0f;
      P3[j] = 0.0f; P3[1024 + j] = 0.0f; P3[2048 + j] = 0.0f; P3[3072 + j] = 0.0f;
      float cn = sigm(gf) * c2[b * 1024 + j] + sigm(gi) * tanhf(gg);
      float hn = sigm(go) * tanhf(cn);
      c2[b * 1024 + j] = cn;
      bf16 hh = __float2bfloat16(hn);
      h2h[b * 1024 + j] = hh;
      h2l[b * 1024 + j] = __float2bfloat16(hn - __bfloat162float(hh));
      if (k == 64) dout[b * 1024 + j] = hn;
    }
  }
}

// ---------------------------------------------------------------------------
extern "C" void kernel_launch(void* const* d_in, const int* in_sizes, int n_in,
                              void* d_out, int out_size, void* d_ws, size_t ws_size,
                              hipStream_t stream) {
  const float* video = (const float*)d_in[0];
  const float* Wemb  = (const float*)d_in[1];
  const float* bemb  = (const float*)d_in[2];
  const float* Wih1  = (const float*)d_in[3];
  const float* Whh1  = (const float*)d_in[4];
  const float* b1    = (const float*)d_in[5];
  const float* Wsi   = (const float*)d_in[6];
  const float* Wsh   = (const float*)d_in[7];
  const float* bbd   = (const float*)d_in[8];
  const float* vs    = (const float*)d_in[9];
  const float* Wih2  = (const float*)d_in[10];
  const float* Whh2  = (const float*)d_in[11];
  float* dout = (float*)d_out;

  static const int exp_sizes[12] = {
    128 * 64 * 2048, 1024 * 2048, 1024, 4096 * 1024, 4096 * 1024, 4096,
    512 * 1024, 512 * 1024, 512, 512, 4096 * 1024, 4096 * 1024 };
  int bad = -1;
  if (n_in != 12) bad = 99;
  else if (out_size != 131072) bad = 98;
  else
    for (int i = 0; i < 12; ++i)
      if (in_sizes[i] != exp_sizes[i]) { bad = i; break; }
  if (bad >= 0) {
    k_diag<<<1, 64, 0, stream>>>(dout, 10000.0f + (float)bad);
    return;
  }

  char* ws = (char*)d_ws;
  size_t off = 0;
  auto alloc = [&](size_t bytes) {
    char* p = ws + off;
    off += (bytes + 255) & ~(size_t)255;
    return p;
  };
  // zero region (state), memset each launch
  bf16*  h1nh = (bf16*)alloc(262144);
  bf16*  h1nl = (bf16*)alloc(262144);
  bf16*  h2h  = (bf16*)alloc(262144);
  bf16*  h2l  = (bf16*)alloc(262144);
  float* c2   = (float*)alloc(524288);
  float* craw = (float*)alloc(524288);
  float* sm   = (float*)alloc(512);
  const size_t zeroBytes = off;
  // rest (written before read every launch)
  double* u    = (double*)alloc(8192);
  double* wvv  = (double*)alloc(8192);
  double* cbdp = (double*)alloc(256);
  float* rdm   = (float*)alloc(64 * 128 * 4);
  bf16* w1hh_h = (bf16*)alloc(8388608);
  bf16* w1hh_l = (bf16*)alloc(8388608);
  bf16* w2ih_h = (bf16*)alloc(8388608);
  bf16* w2hh_h = (bf16*)alloc(8388608);
  float* R     = (float*)alloc(4 * 2097152);            // 4 partials, 8.4 MB
  float* Gxf   = (float*)alloc(8 * 2097152);            // Gx ring / embed Ep alias
  bf16* vhi    = (bf16*)alloc(8 * 131072 * 2);          // v ring, 8 slots
  bf16* vlo    = (bf16*)alloc(8 * 131072 * 2);

  if (ws_size < off) {
    k_diag<<<1, 64, 0, stream>>>(dout, 100.0f + (float)(ws_size >> 20));
    return;
  }

  (void)hipMemsetAsync(d_ws, 0, zeroBytes, stream);
  (void)hipMemsetAsync(R, 0, 4 * 2097152, stream);      // atomic accumulators
  k_uw<<<9, 256, 0, stream>>>(Wsi, Wsh, bbd, vs, u, wvv, cbdp);
  k_wsplit<<<12288, 256, 0, stream>>>(Whh1, Wih2, Whh2,
                                      w1hh_h, w1hh_l, w2ih_h, w2hh_h);

  for (int k = 0; k <= 64; ++k) {
    if (k < 64 && (k & 7) == 0) {
      k_embed<<<256, 256, 0, stream>>>(video, Wemb, Gxf, k);          // Ep alias
      k_efin<<<1024, 256, 0, stream>>>(Gxf, bemb, vhi, vlo);
      k_xgates<<<256, 256, 0, stream>>>(vhi, vlo, Wih1, Gxf);         // writes Gx
    }
    if (k > 0)
      k_step<<<256, 256, 0, stream>>>(h1nh, h1nl, h2h, h2l,
                                      w1hh_h, w1hh_l, w2ih_h, w2hh_h, sm, R, k);
    k_elem<<<128, 512, 0, stream>>>(R, Gxf, vhi, vlo, u, cbdp, craw,
                                    h1nh, h1nl, sm, c2, h2h, h2l,
                                    rdm, wvv, b1, dout, k);
  }
}